// Round 2
// baseline (1839.294 us; speedup 1.0000x reference)
//
#include <hip/hip_runtime.h>

#define N_NODES 100000
#define N_EDGES 1000000
#define IN_DIM 32
#define HID_DIM 64

// ---------------- scatter (sum + count) kernels ----------------

__global__ __launch_bounds__(256) void k_scatter1(
    const float* __restrict__ x,     // [N][32]
    const int* __restrict__ ei,      // [2][E]
    const int* __restrict__ ea,      // [E][2]
    float* __restrict__ agg,         // [2][N][32]
    float* __restrict__ cnt)         // [2][N]
{
    int t = blockIdx.x * 256 + threadIdx.x;
    int e = t >> 5;
    int f = t & 31;
    if (e >= N_EDGES) return;
    int src = ei[e];
    int dst = ei[N_EDGES + e];
    int rel = ea[2 * e + 1];
    float v = x[(size_t)src * IN_DIM + f];
    atomicAdd(&agg[((size_t)rel * N_NODES + (size_t)dst) * IN_DIM + f], v);
    if (f == 0) atomicAdd(&cnt[(size_t)rel * N_NODES + dst], 1.0f);
}

__global__ __launch_bounds__(256) void k_scatter2(
    const float* __restrict__ h1,    // [N][64]
    const int* __restrict__ ei,
    const int* __restrict__ ea,
    float* __restrict__ agg)         // [2][N][64]
{
    int t = blockIdx.x * 256 + threadIdx.x;
    int e = t >> 6;
    int f = t & 63;
    if (e >= N_EDGES) return;
    int src = ei[e];
    int dst = ei[N_EDGES + e];
    int rel = ea[2 * e + 1];
    float v = h1[(size_t)src * HID_DIM + f];
    atomicAdd(&agg[((size_t)rel * N_NODES + (size_t)dst) * HID_DIM + f], v);
}

// ---------------- node-update kernels ----------------
// 256 threads = 4 waves. Lane j (0..63) = output feature; each wave register-
// blocks 4 nodes so the 12 per-k weight LDS reads are amortized over 4 nodes.
// All locals are plain scalars / float4 members — NO address-of-local indexing
// (round-1 version spilled 48 floats/thread to scratch -> 3.1 GB HBM traffic).

#define NODES_PER_BLOCK 64   // 4 waves * 4 nodes * 4 iters

// One node's 4-k contribution for one matrix, via float4 members.
#define ACC4(acc, v, wa, wb, wc_, wd) \
    acc = fmaf((v).x, wa, acc);       \
    acc = fmaf((v).y, wb, acc);       \
    acc = fmaf((v).z, wc_, acc);      \
    acc = fmaf((v).w, wd, acc);

__global__ __launch_bounds__(256) void k_layer1(
    const float* __restrict__ x,      // [N][32]
    const float* __restrict__ agg,    // [2][N][32]
    const float* __restrict__ cnt,    // [2][N]
    const float* __restrict__ root1,  // [32][64]
    const float* __restrict__ W1,     // [2][32][64]
    const float* __restrict__ b1,     // [64]
    float* __restrict__ h1)           // [N][64]
{
    __shared__ float wR[IN_DIM * HID_DIM];
    __shared__ float w0[IN_DIM * HID_DIM];
    __shared__ float w1s[IN_DIM * HID_DIM];
    int tid = threadIdx.x;
    for (int i = tid; i < IN_DIM * HID_DIM; i += 256) {
        wR[i]  = root1[i];
        w0[i]  = W1[i];
        w1s[i] = W1[IN_DIM * HID_DIM + i];
    }
    __syncthreads();

    int j   = tid & 63;   // output feature
    int sub = tid >> 6;   // wave id 0..3
    float bj = b1[j];
    int base = blockIdx.x * NODES_PER_BLOCK;

    for (int it = 0; it < 4; ++it) {
        int n0 = base + it * 16 + sub * 4;   // group of 4 nodes (N%4==0)
        if (n0 >= N_NODES) continue;

        float accR0 = 0, accR1 = 0, accR2 = 0, accR3 = 0;
        float acc00 = 0, acc01 = 0, acc02 = 0, acc03 = 0;
        float acc10 = 0, acc11 = 0, acc12 = 0, acc13 = 0;

#pragma unroll
        for (int kk = 0; kk < IN_DIM / 4; ++kk) {
            int kbase = kk * 4;
            float wRa = wR[(kbase + 0) * 64 + j];
            float wRb = wR[(kbase + 1) * 64 + j];
            float wRc = wR[(kbase + 2) * 64 + j];
            float wRd = wR[(kbase + 3) * 64 + j];
            float w0a = w0[(kbase + 0) * 64 + j];
            float w0b = w0[(kbase + 1) * 64 + j];
            float w0c = w0[(kbase + 2) * 64 + j];
            float w0d = w0[(kbase + 3) * 64 + j];
            float w1a = w1s[(kbase + 0) * 64 + j];
            float w1b = w1s[(kbase + 1) * 64 + j];
            float w1c = w1s[(kbase + 2) * 64 + j];
            float w1d = w1s[(kbase + 3) * 64 + j];

#define L1_NODE(i, accR, acc0, acc1)                                              \
            {                                                                     \
                size_t n = (size_t)(n0 + i);                                      \
                float4 xa = *(const float4*)(x   + n * IN_DIM + kbase);           \
                float4 q0 = *(const float4*)(agg + n * IN_DIM + kbase);           \
                float4 q1 = *(const float4*)(agg + ((size_t)N_NODES + n) * IN_DIM + kbase); \
                ACC4(accR, xa, wRa, wRb, wRc, wRd)                                \
                ACC4(acc0, q0, w0a, w0b, w0c, w0d)                                \
                ACC4(acc1, q1, w1a, w1b, w1c, w1d)                                \
            }
            L1_NODE(0, accR0, acc00, acc10)
            L1_NODE(1, accR1, acc01, acc11)
            L1_NODE(2, accR2, acc02, acc12)
            L1_NODE(3, accR3, acc03, acc13)
#undef L1_NODE
        }

#define L1_OUT(i, accR, acc0, acc1)                                               \
        {                                                                         \
            int n = n0 + i;                                                       \
            float ic0 = 1.0f / fmaxf(cnt[n], 1.0f);                               \
            float ic1 = 1.0f / fmaxf(cnt[N_NODES + n], 1.0f);                     \
            float o = accR + bj + acc0 * ic0 + acc1 * ic1;                        \
            h1[(size_t)n * HID_DIM + j] = fmaxf(o, 0.0f);                         \
        }
        L1_OUT(0, accR0, acc00, acc10)
        L1_OUT(1, accR1, acc01, acc11)
        L1_OUT(2, accR2, acc02, acc12)
        L1_OUT(3, accR3, acc03, acc13)
#undef L1_OUT
    }
}

__global__ __launch_bounds__(256) void k_layer2_cls(
    const float* __restrict__ h1,     // [N][64]
    const float* __restrict__ agg,    // [2][N][64]
    const float* __restrict__ cnt,    // [2][N]
    const float* __restrict__ root2,  // [64][64]
    const float* __restrict__ W2,     // [2][64][64]
    const float* __restrict__ b2,     // [64]
    const float* __restrict__ Wc,     // [64][2]
    const float* __restrict__ bc,     // [2]
    float* __restrict__ out)          // [N][2]
{
    __shared__ float wR[HID_DIM * HID_DIM];
    __shared__ float w0[HID_DIM * HID_DIM];
    __shared__ float w1s[HID_DIM * HID_DIM];
    __shared__ float wc[HID_DIM * 2];
    int tid = threadIdx.x;
    for (int i = tid; i < HID_DIM * HID_DIM; i += 256) {
        wR[i]  = root2[i];
        w0[i]  = W2[i];
        w1s[i] = W2[HID_DIM * HID_DIM + i];
    }
    if (tid < HID_DIM * 2) wc[tid] = Wc[tid];
    __syncthreads();

    int j   = tid & 63;
    int sub = tid >> 6;
    float bj  = b2[j];
    float bc0 = bc[0], bc1 = bc[1];
    int base = blockIdx.x * NODES_PER_BLOCK;

    for (int it = 0; it < 4; ++it) {
        int n0 = base + it * 16 + sub * 4;
        if (n0 >= N_NODES) continue;

        float accR0 = 0, accR1 = 0, accR2 = 0, accR3 = 0;
        float acc00 = 0, acc01 = 0, acc02 = 0, acc03 = 0;
        float acc10 = 0, acc11 = 0, acc12 = 0, acc13 = 0;

#pragma unroll
        for (int kk = 0; kk < HID_DIM / 4; ++kk) {
            int kbase = kk * 4;
            float wRa = wR[(kbase + 0) * 64 + j];
            float wRb = wR[(kbase + 1) * 64 + j];
            float wRc = wR[(kbase + 2) * 64 + j];
            float wRd = wR[(kbase + 3) * 64 + j];
            float w0a = w0[(kbase + 0) * 64 + j];
            float w0b = w0[(kbase + 1) * 64 + j];
            float w0c = w0[(kbase + 2) * 64 + j];
            float w0d = w0[(kbase + 3) * 64 + j];
            float w1a = w1s[(kbase + 0) * 64 + j];
            float w1b = w1s[(kbase + 1) * 64 + j];
            float w1c = w1s[(kbase + 2) * 64 + j];
            float w1d = w1s[(kbase + 3) * 64 + j];

#define L2_NODE(i, accR, acc0, acc1)                                              \
            {                                                                     \
                size_t n = (size_t)(n0 + i);                                      \
                float4 xa = *(const float4*)(h1  + n * HID_DIM + kbase);          \
                float4 q0 = *(const float4*)(agg + n * HID_DIM + kbase);          \
                float4 q1 = *(const float4*)(agg + ((size_t)N_NODES + n) * HID_DIM + kbase); \
                ACC4(accR, xa, wRa, wRb, wRc, wRd)                                \
                ACC4(acc0, q0, w0a, w0b, w0c, w0d)                                \
                ACC4(acc1, q1, w1a, w1b, w1c, w1d)                                \
            }
            L2_NODE(0, accR0, acc00, acc10)
            L2_NODE(1, accR1, acc01, acc11)
            L2_NODE(2, accR2, acc02, acc12)
            L2_NODE(3, accR3, acc03, acc13)
#undef L2_NODE
        }

#define L2_OUT(i, accR, acc0, acc1)                                               \
        {                                                                         \
            int n = n0 + i;                                                       \
            float ic0 = 1.0f / fmaxf(cnt[n], 1.0f);                               \
            float ic1 = 1.0f / fmaxf(cnt[N_NODES + n], 1.0f);                     \
            float h2 = fmaxf(accR + bj + acc0 * ic0 + acc1 * ic1, 0.0f);          \
            float v0 = h2 * wc[2 * j];                                            \
            float v1 = h2 * wc[2 * j + 1];                                        \
            for (int off = 32; off >= 1; off >>= 1) {                             \
                v0 += __shfl_xor(v0, off);                                        \
                v1 += __shfl_xor(v1, off);                                        \
            }                                                                     \
            if (j == 0) {                                                         \
                out[(size_t)n * 2 + 0] = v0 + bc0;                                \
                out[(size_t)n * 2 + 1] = v1 + bc1;                                \
            }                                                                     \
        }
        L2_OUT(0, accR0, acc00, acc10)
        L2_OUT(1, accR1, acc01, acc11)
        L2_OUT(2, accR2, acc02, acc12)
        L2_OUT(3, accR3, acc03, acc13)
#undef L2_OUT
    }
}

// ---------------- launch ----------------

extern "C" void kernel_launch(void* const* d_in, const int* in_sizes, int n_in,
                              void* d_out, int out_size, void* d_ws, size_t ws_size,
                              hipStream_t stream) {
    const float* x     = (const float*)d_in[0];
    const int*   ei    = (const int*)d_in[1];
    const int*   ea    = (const int*)d_in[2];
    const float* W1    = (const float*)d_in[3];
    const float* root1 = (const float*)d_in[4];
    const float* b1    = (const float*)d_in[5];
    const float* W2    = (const float*)d_in[6];
    const float* root2 = (const float*)d_in[7];
    const float* b2    = (const float*)d_in[8];
    const float* Wc    = (const float*)d_in[9];
    const float* bc    = (const float*)d_in[10];
    float* out = (float*)d_out;

    // ws layout (bytes):
    //   cnt : [0, 800000)                      2*N f32
    //   agg : [800000, 800000+51200000)        2*N*64 f32 (layer1 uses first 2*N*32)
    //   h1  : [52000000, 77600000)             N*64 f32
    char* ws = (char*)d_ws;
    float* cnt = (float*)(ws);
    float* agg = (float*)(ws + 800000);
    float* h1  = (float*)(ws + 800000 + 51200000);

    // zero cnt + layer-1 agg (contiguous: 800000 + 2*N*32*4 bytes)
    hipMemsetAsync(cnt, 0, 800000 + 2ull * N_NODES * IN_DIM * 4, stream);

    k_scatter1<<<(N_EDGES * 32) / 256, 256, 0, stream>>>(x, ei, ea, agg, cnt);

    int grid_nodes = (N_NODES + NODES_PER_BLOCK - 1) / NODES_PER_BLOCK;  // 1563
    k_layer1<<<grid_nodes, 256, 0, stream>>>(x, agg, cnt, root1, W1, b1, h1);

    hipMemsetAsync(agg, 0, 2ull * N_NODES * HID_DIM * 4, stream);

    k_scatter2<<<(N_EDGES * 64) / 256, 256, 0, stream>>>(h1, ei, ea, agg);

    k_layer2_cls<<<grid_nodes, 256, 0, stream>>>(h1, agg, cnt, root2, W2, b2, Wc, bc, out);
}

// Round 3
// 643.672 us; speedup vs baseline: 2.8575x; 2.8575x over previous
//
#include <hip/hip_runtime.h>

#define N_NODES 100000
#define N_EDGES 1000000
#define IN_DIM 32
#define HID_DIM 64

// ---------------- scatter (sum + count) kernels ----------------

__global__ __launch_bounds__(256) void k_scatter1(
    const float* __restrict__ x,     // [N][32]
    const int* __restrict__ ei,      // [2][E]
    const int* __restrict__ ea,      // [E][2]
    float* __restrict__ agg,         // [2][N][32]
    float* __restrict__ cnt)         // [2][N]
{
    int t = blockIdx.x * 256 + threadIdx.x;
    int e = t >> 5;
    int f = t & 31;
    if (e >= N_EDGES) return;
    int src = ei[e];
    int dst = ei[N_EDGES + e];
    int rel = ea[2 * e + 1];
    float v = x[(size_t)src * IN_DIM + f];
    atomicAdd(&agg[((size_t)rel * N_NODES + (size_t)dst) * IN_DIM + f], v);
    if (f == 0) atomicAdd(&cnt[(size_t)rel * N_NODES + dst], 1.0f);
}

__global__ __launch_bounds__(256) void k_scatter2(
    const float* __restrict__ h1,    // [N][64]
    const int* __restrict__ ei,
    const int* __restrict__ ea,
    float* __restrict__ agg)         // [2][N][64]
{
    int t = blockIdx.x * 256 + threadIdx.x;
    int e = t >> 6;
    int f = t & 63;
    if (e >= N_EDGES) return;
    int src = ei[e];
    int dst = ei[N_EDGES + e];
    int rel = ea[2 * e + 1];
    float v = h1[(size_t)src * HID_DIM + f];
    atomicAdd(&agg[((size_t)rel * N_NODES + (size_t)dst) * HID_DIM + f], v);
}

// ---------------- node-update kernels ----------------
// 256 threads = 4 waves. Lane j (0..63) = output feature; each wave register-
// blocks 4 nodes so the 12 per-k weight LDS reads are amortized over 4 nodes.
//
// CRITICAL: the k-loop must NOT be fully unrolled. With #pragma unroll the
// compiler flattens 16 iters x 12 float4 loads into one block, hoists all
// loads, exceeds 256 VGPRs and spills ~3 KB/thread -> 3.1 GB scratch HBM
// traffic, 1390 us (rounds 0-1). unroll 1 bounds in-flight loads to 12.

#define NODES_PER_BLOCK 64   // 4 waves * 4 nodes * 4 iters

#define ACC4(acc, v, wa, wb, wc_, wd) \
    acc = fmaf((v).x, wa, acc);       \
    acc = fmaf((v).y, wb, acc);       \
    acc = fmaf((v).z, wc_, acc);      \
    acc = fmaf((v).w, wd, acc);

__global__ __launch_bounds__(256, 4) void k_layer1(
    const float* __restrict__ x,      // [N][32]
    const float* __restrict__ agg,    // [2][N][32]
    const float* __restrict__ cnt,    // [2][N]
    const float* __restrict__ root1,  // [32][64]
    const float* __restrict__ W1,     // [2][32][64]
    const float* __restrict__ b1,     // [64]
    float* __restrict__ h1)           // [N][64]
{
    __shared__ float wR[IN_DIM * HID_DIM];
    __shared__ float w0[IN_DIM * HID_DIM];
    __shared__ float w1s[IN_DIM * HID_DIM];
    int tid = threadIdx.x;
    for (int i = tid; i < IN_DIM * HID_DIM; i += 256) {
        wR[i]  = root1[i];
        w0[i]  = W1[i];
        w1s[i] = W1[IN_DIM * HID_DIM + i];
    }
    __syncthreads();

    int j   = tid & 63;   // output feature
    int sub = tid >> 6;   // wave id 0..3
    float bj = b1[j];
    int base = blockIdx.x * NODES_PER_BLOCK;

    for (int it = 0; it < 4; ++it) {
        int n0 = base + it * 16 + sub * 4;
        if (n0 >= N_NODES) continue;

        float accR0 = 0, accR1 = 0, accR2 = 0, accR3 = 0;
        float acc00 = 0, acc01 = 0, acc02 = 0, acc03 = 0;
        float acc10 = 0, acc11 = 0, acc12 = 0, acc13 = 0;

#pragma unroll 1
        for (int kk = 0; kk < IN_DIM / 4; ++kk) {
            int kbase = kk * 4;
            float wRa = wR[(kbase + 0) * 64 + j];
            float wRb = wR[(kbase + 1) * 64 + j];
            float wRc = wR[(kbase + 2) * 64 + j];
            float wRd = wR[(kbase + 3) * 64 + j];
            float w0a = w0[(kbase + 0) * 64 + j];
            float w0b = w0[(kbase + 1) * 64 + j];
            float w0c = w0[(kbase + 2) * 64 + j];
            float w0d = w0[(kbase + 3) * 64 + j];
            float w1a = w1s[(kbase + 0) * 64 + j];
            float w1b = w1s[(kbase + 1) * 64 + j];
            float w1c = w1s[(kbase + 2) * 64 + j];
            float w1d = w1s[(kbase + 3) * 64 + j];

#define L1_NODE(i, accR, acc0, acc1)                                              \
            {                                                                     \
                size_t n = (size_t)(n0 + i);                                      \
                float4 xa = *(const float4*)(x   + n * IN_DIM + kbase);           \
                float4 q0 = *(const float4*)(agg + n * IN_DIM + kbase);           \
                float4 q1 = *(const float4*)(agg + ((size_t)N_NODES + n) * IN_DIM + kbase); \
                ACC4(accR, xa, wRa, wRb, wRc, wRd)                                \
                ACC4(acc0, q0, w0a, w0b, w0c, w0d)                                \
                ACC4(acc1, q1, w1a, w1b, w1c, w1d)                                \
            }
            L1_NODE(0, accR0, acc00, acc10)
            L1_NODE(1, accR1, acc01, acc11)
            L1_NODE(2, accR2, acc02, acc12)
            L1_NODE(3, accR3, acc03, acc13)
#undef L1_NODE
        }

#define L1_OUT(i, accR, acc0, acc1)                                               \
        {                                                                         \
            int n = n0 + i;                                                       \
            float ic0 = 1.0f / fmaxf(cnt[n], 1.0f);                               \
            float ic1 = 1.0f / fmaxf(cnt[N_NODES + n], 1.0f);                     \
            float o = accR + bj + acc0 * ic0 + acc1 * ic1;                        \
            h1[(size_t)n * HID_DIM + j] = fmaxf(o, 0.0f);                         \
        }
        L1_OUT(0, accR0, acc00, acc10)
        L1_OUT(1, accR1, acc01, acc11)
        L1_OUT(2, accR2, acc02, acc12)
        L1_OUT(3, accR3, acc03, acc13)
#undef L1_OUT
    }
}

__global__ __launch_bounds__(256, 4) void k_layer2_cls(
    const float* __restrict__ h1,     // [N][64]
    const float* __restrict__ agg,    // [2][N][64]
    const float* __restrict__ cnt,    // [2][N]
    const float* __restrict__ root2,  // [64][64]
    const float* __restrict__ W2,     // [2][64][64]
    const float* __restrict__ b2,     // [64]
    const float* __restrict__ Wc,     // [64][2]
    const float* __restrict__ bc,     // [2]
    float* __restrict__ out)          // [N][2]
{
    __shared__ float wR[HID_DIM * HID_DIM];
    __shared__ float w0[HID_DIM * HID_DIM];
    __shared__ float w1s[HID_DIM * HID_DIM];
    __shared__ float wc[HID_DIM * 2];
    int tid = threadIdx.x;
    for (int i = tid; i < HID_DIM * HID_DIM; i += 256) {
        wR[i]  = root2[i];
        w0[i]  = W2[i];
        w1s[i] = W2[HID_DIM * HID_DIM + i];
    }
    if (tid < HID_DIM * 2) wc[tid] = Wc[tid];
    __syncthreads();

    int j   = tid & 63;
    int sub = tid >> 6;
    float bj  = b2[j];
    float bc0 = bc[0], bc1 = bc[1];
    int base = blockIdx.x * NODES_PER_BLOCK;

    for (int it = 0; it < 4; ++it) {
        int n0 = base + it * 16 + sub * 4;
        if (n0 >= N_NODES) continue;

        float accR0 = 0, accR1 = 0, accR2 = 0, accR3 = 0;
        float acc00 = 0, acc01 = 0, acc02 = 0, acc03 = 0;
        float acc10 = 0, acc11 = 0, acc12 = 0, acc13 = 0;

#pragma unroll 1
        for (int kk = 0; kk < HID_DIM / 4; ++kk) {
            int kbase = kk * 4;
            float wRa = wR[(kbase + 0) * 64 + j];
            float wRb = wR[(kbase + 1) * 64 + j];
            float wRc = wR[(kbase + 2) * 64 + j];
            float wRd = wR[(kbase + 3) * 64 + j];
            float w0a = w0[(kbase + 0) * 64 + j];
            float w0b = w0[(kbase + 1) * 64 + j];
            float w0c = w0[(kbase + 2) * 64 + j];
            float w0d = w0[(kbase + 3) * 64 + j];
            float w1a = w1s[(kbase + 0) * 64 + j];
            float w1b = w1s[(kbase + 1) * 64 + j];
            float w1c = w1s[(kbase + 2) * 64 + j];
            float w1d = w1s[(kbase + 3) * 64 + j];

#define L2_NODE(i, accR, acc0, acc1)                                              \
            {                                                                     \
                size_t n = (size_t)(n0 + i);                                      \
                float4 xa = *(const float4*)(h1  + n * HID_DIM + kbase);          \
                float4 q0 = *(const float4*)(agg + n * HID_DIM + kbase);          \
                float4 q1 = *(const float4*)(agg + ((size_t)N_NODES + n) * HID_DIM + kbase); \
                ACC4(accR, xa, wRa, wRb, wRc, wRd)                                \
                ACC4(acc0, q0, w0a, w0b, w0c, w0d)                                \
                ACC4(acc1, q1, w1a, w1b, w1c, w1d)                                \
            }
            L2_NODE(0, accR0, acc00, acc10)
            L2_NODE(1, accR1, acc01, acc11)
            L2_NODE(2, accR2, acc02, acc12)
            L2_NODE(3, accR3, acc03, acc13)
#undef L2_NODE
        }

#define L2_OUT(i, accR, acc0, acc1)                                               \
        {                                                                         \
            int n = n0 + i;                                                       \
            float ic0 = 1.0f / fmaxf(cnt[n], 1.0f);                               \
            float ic1 = 1.0f / fmaxf(cnt[N_NODES + n], 1.0f);                     \
            float h2 = fmaxf(accR + bj + acc0 * ic0 + acc1 * ic1, 0.0f);          \
            float v0 = h2 * wc[2 * j];                                            \
            float v1 = h2 * wc[2 * j + 1];                                        \
            for (int off = 32; off >= 1; off >>= 1) {                             \
                v0 += __shfl_xor(v0, off);                                        \
                v1 += __shfl_xor(v1, off);                                        \
            }                                                                     \
            if (j == 0) {                                                         \
                out[(size_t)n * 2 + 0] = v0 + bc0;                                \
                out[(size_t)n * 2 + 1] = v1 + bc1;                                \
            }                                                                     \
        }
        L2_OUT(0, accR0, acc00, acc10)
        L2_OUT(1, accR1, acc01, acc11)
        L2_OUT(2, accR2, acc02, acc12)
        L2_OUT(3, accR3, acc03, acc13)
#undef L2_OUT
    }
}

// ---------------- launch ----------------

extern "C" void kernel_launch(void* const* d_in, const int* in_sizes, int n_in,
                              void* d_out, int out_size, void* d_ws, size_t ws_size,
                              hipStream_t stream) {
    const float* x     = (const float*)d_in[0];
    const int*   ei    = (const int*)d_in[1];
    const int*   ea    = (const int*)d_in[2];
    const float* W1    = (const float*)d_in[3];
    const float* root1 = (const float*)d_in[4];
    const float* b1    = (const float*)d_in[5];
    const float* W2    = (const float*)d_in[6];
    const float* root2 = (const float*)d_in[7];
    const float* b2    = (const float*)d_in[8];
    const float* Wc    = (const float*)d_in[9];
    const float* bc    = (const float*)d_in[10];
    float* out = (float*)d_out;

    // ws layout (bytes):
    //   cnt : [0, 800000)                      2*N f32
    //   agg : [800000, 800000+51200000)        2*N*64 f32 (layer1 uses first 2*N*32)
    //   h1  : [52000000, 77600000)             N*64 f32
    char* ws = (char*)d_ws;
    float* cnt = (float*)(ws);
    float* agg = (float*)(ws + 800000);
    float* h1  = (float*)(ws + 800000 + 51200000);

    // zero cnt + layer-1 agg (contiguous: 800000 + 2*N*32*4 bytes)
    hipMemsetAsync(cnt, 0, 800000 + 2ull * N_NODES * IN_DIM * 4, stream);

    k_scatter1<<<(N_EDGES * 32) / 256, 256, 0, stream>>>(x, ei, ea, agg, cnt);

    int grid_nodes = (N_NODES + NODES_PER_BLOCK - 1) / NODES_PER_BLOCK;  // 1563
    k_layer1<<<grid_nodes, 256, 0, stream>>>(x, agg, cnt, root1, W1, b1, h1);

    hipMemsetAsync(agg, 0, 2ull * N_NODES * HID_DIM * 4, stream);

    k_scatter2<<<(N_EDGES * 64) / 256, 256, 0, stream>>>(h1, ei, ea, agg);

    k_layer2_cls<<<grid_nodes, 256, 0, stream>>>(h1, agg, cnt, root2, W2, b2, Wc, bc, out);
}

// Round 4
// 590.945 us; speedup vs baseline: 3.1125x; 1.0892x over previous
//
#include <hip/hip_runtime.h>

#define N_NODES 100000
#define N_EDGES 1000000
#define IN_DIM 32
#define HID_DIM 64
#define N2 (2 * N_NODES)          // (rel,node) buckets

// ============ CSR build: histogram -> scan -> fill ============

__global__ __launch_bounds__(256) void k_count(
    const int* __restrict__ ei, const int* __restrict__ ea,
    int* __restrict__ deg)
{
    int e = blockIdx.x * 256 + threadIdx.x;
    if (e >= N_EDGES) return;
    int dst = ei[N_EDGES + e];
    int rel = ea[2 * e + 1];
    atomicAdd(&deg[rel * N_NODES + dst], 1);
}

__global__ __launch_bounds__(256) void k_scan_local(
    const int* __restrict__ deg, int* __restrict__ offs, int* __restrict__ bsum)
{
    int t = threadIdx.x;
    int i = blockIdx.x * 256 + t;
    int v = (i < N2) ? deg[i] : 0;
    int lane = t & 63, w = t >> 6;
    int s = v;
#pragma unroll
    for (int off = 1; off < 64; off <<= 1) {
        int u = __shfl_up(s, off);
        if (lane >= off) s += u;
    }
    __shared__ int wsum[4];
    if (lane == 63) wsum[w] = s;
    __syncthreads();
    int add = 0;
    for (int ww = 0; ww < w; ++ww) add += wsum[ww];
    s += add;
    if (i < N2) offs[i] = s - v;                 // block-local exclusive
    if (t == 255) bsum[blockIdx.x] = s;          // block total
}

__global__ __launch_bounds__(64) void k_scan_blocks(int* __restrict__ bsum, int nblk)
{
    int lane = threadIdx.x;  // single wave
    int carry = 0;
    for (int base = 0; base < nblk; base += 64) {
        int i = base + lane;
        int v = (i < nblk) ? bsum[i] : 0;
        int s = v;
#pragma unroll
        for (int off = 1; off < 64; off <<= 1) {
            int u = __shfl_up(s, off);
            if (lane >= off) s += u;
        }
        if (i < nblk) bsum[i] = carry + s - v;   // exclusive
        carry += __shfl(s, 63);
    }
}

__global__ __launch_bounds__(256) void k_scan_add(
    int* __restrict__ offs, const int* __restrict__ bsum, int* __restrict__ cursor)
{
    int i = blockIdx.x * 256 + threadIdx.x;
    if (i >= N2) return;
    int o = offs[i] + bsum[i >> 8];
    offs[i] = o;
    cursor[i] = o;
}

__global__ __launch_bounds__(256) void k_fill(
    const int* __restrict__ ei, const int* __restrict__ ea,
    int* __restrict__ cursor, int* __restrict__ elist)
{
    int e = blockIdx.x * 256 + threadIdx.x;
    if (e >= N_EDGES) return;
    int src = ei[e];
    int dst = ei[N_EDGES + e];
    int rel = ea[2 * e + 1];
    int pos = atomicAdd(&cursor[rel * N_NODES + dst], 1);
    elist[pos] = src;
}

// ============ fused layers: gather-mean + matmul + act ============
// One wave per node. Lane = feature. Edge list index is wave-uniform
// (node forced uniform via readfirstlane) -> scalar loads for elist.
// Matmul: broadcast mean[k]/self[k] via __shfl(reg, k) (readlane when
// unrolled) against LDS-staged weight columns.

__global__ __launch_bounds__(1024) void k_fused1(
    const float* __restrict__ x,      // [N][32]
    const int* __restrict__ offs,     // [2N]
    const int* __restrict__ deg,      // [2N]
    const int* __restrict__ elist,    // [E]
    const float* __restrict__ root1,  // [32][64]
    const float* __restrict__ W1,     // [2][32][64]
    const float* __restrict__ b1,     // [64]
    float* __restrict__ h1)           // [N][64]
{
    __shared__ float wR[IN_DIM * HID_DIM];
    __shared__ float w0[IN_DIM * HID_DIM];
    __shared__ float w1s[IN_DIM * HID_DIM];
    int tid = threadIdx.x;
    for (int i = tid; i < IN_DIM * HID_DIM; i += 1024) {
        wR[i]  = root1[i];
        w0[i]  = W1[i];
        w1s[i] = W1[IN_DIM * HID_DIM + i];
    }
    __syncthreads();

    int lane = tid & 63;
    int node = __builtin_amdgcn_readfirstlane(blockIdx.x * 16 + (tid >> 6));
    if (node >= N_NODES) return;

    int f = lane & 31, slot = lane >> 5;

    float xs = x[(size_t)node * IN_DIM + f];   // self row (dup across slots)

    float mean0, mean1;
#pragma unroll
    for (int r = 0; r < 2; ++r) {
        int s0 = offs[r * N_NODES + node];
        int d0 = deg[r * N_NODES + node];
        int e0 = s0 + d0;
        float a = 0.0f;
        for (int k = s0 + slot; k < e0; k += 2)
            a += x[(size_t)elist[k] * IN_DIM + f];
        a += __shfl_xor(a, 32);                // combine the two slots
        float m = a / fmaxf((float)d0, 1.0f);
        if (r == 0) mean0 = m; else mean1 = m;
    }

    int j = lane;
    float acc = b1[j];
#pragma unroll
    for (int k = 0; k < IN_DIM; ++k) {
        float xk = __shfl(xs, k);      // lane k: f=k, slot=0
        float m0 = __shfl(mean0, k);
        float m1 = __shfl(mean1, k);
        acc = fmaf(xk, wR[k * 64 + j],
              fmaf(m0, w0[k * 64 + j],
              fmaf(m1, w1s[k * 64 + j], acc)));
    }
    h1[(size_t)node * HID_DIM + j] = fmaxf(acc, 0.0f);
}

__global__ __launch_bounds__(1024) void k_fused2(
    const float* __restrict__ h1,     // [N][64]
    const int* __restrict__ offs,
    const int* __restrict__ deg,
    const int* __restrict__ elist,
    const float* __restrict__ root2,  // [64][64]
    const float* __restrict__ W2,     // [2][64][64]
    const float* __restrict__ b2,     // [64]
    const float* __restrict__ Wc,     // [64][2]
    const float* __restrict__ bc,     // [2]
    float* __restrict__ out)          // [N][2]
{
    __shared__ float wR[HID_DIM * HID_DIM];
    __shared__ float w0[HID_DIM * HID_DIM];
    __shared__ float w1s[HID_DIM * HID_DIM];
    __shared__ float wc[HID_DIM * 2];
    int tid = threadIdx.x;
    for (int i = tid; i < HID_DIM * HID_DIM; i += 1024) {
        wR[i]  = root2[i];
        w0[i]  = W2[i];
        w1s[i] = W2[HID_DIM * HID_DIM + i];
    }
    if (tid < HID_DIM * 2) wc[tid] = Wc[tid];
    __syncthreads();

    int lane = tid & 63;
    int node = __builtin_amdgcn_readfirstlane(blockIdx.x * 16 + (tid >> 6));
    if (node >= N_NODES) return;

    int j = lane;
    float xs = h1[(size_t)node * HID_DIM + j];

    float mean0, mean1;
#pragma unroll
    for (int r = 0; r < 2; ++r) {
        int s0 = offs[r * N_NODES + node];
        int d0 = deg[r * N_NODES + node];
        int e0 = s0 + d0;
        float a = 0.0f;
        int k = s0;
        for (; k + 2 <= e0; k += 2) {          // unroll-2 for load ILP
            int sA = elist[k], sB = elist[k + 1];
            float vA = h1[(size_t)sA * HID_DIM + j];
            float vB = h1[(size_t)sB * HID_DIM + j];
            a += vA + vB;
        }
        if (k < e0) a += h1[(size_t)elist[k] * HID_DIM + j];
        float m = a / fmaxf((float)d0, 1.0f);
        if (r == 0) mean0 = m; else mean1 = m;
    }

    float acc = b2[j];
#pragma unroll
    for (int k = 0; k < HID_DIM; ++k) {
        float xk = __shfl(xs, k);
        float m0 = __shfl(mean0, k);
        float m1 = __shfl(mean1, k);
        acc = fmaf(xk, wR[k * 64 + j],
              fmaf(m0, w0[k * 64 + j],
              fmaf(m1, w1s[k * 64 + j], acc)));
    }
    float h2 = fmaxf(acc, 0.0f);

    float v0 = h2 * wc[2 * j];
    float v1 = h2 * wc[2 * j + 1];
#pragma unroll
    for (int off = 32; off >= 1; off >>= 1) {
        v0 += __shfl_xor(v0, off);
        v1 += __shfl_xor(v1, off);
    }
    if (j == 0) {
        out[(size_t)node * 2 + 0] = v0 + bc[0];
        out[(size_t)node * 2 + 1] = v1 + bc[1];
    }
}

// ============ launch ============

extern "C" void kernel_launch(void* const* d_in, const int* in_sizes, int n_in,
                              void* d_out, int out_size, void* d_ws, size_t ws_size,
                              hipStream_t stream) {
    const float* x     = (const float*)d_in[0];
    const int*   ei    = (const int*)d_in[1];
    const int*   ea    = (const int*)d_in[2];
    const float* W1    = (const float*)d_in[3];
    const float* root1 = (const float*)d_in[4];
    const float* b1    = (const float*)d_in[5];
    const float* W2    = (const float*)d_in[6];
    const float* root2 = (const float*)d_in[7];
    const float* b2    = (const float*)d_in[8];
    const float* Wc    = (const float*)d_in[9];
    const float* bc    = (const float*)d_in[10];
    float* out = (float*)d_out;

    // ws layout (bytes), all rebuilt every call (ws is poisoned once, never
    // re-poisoned -> every buffer below is fully written before read):
    //   deg    @ 0         : 2N int   (800000)   memset 0 then histogram
    //   offs   @ 800000    : 2N int
    //   cursor @ 1600000   : 2N int
    //   bsum   @ 2400000   : 1024 int (4096)
    //   elist  @ 2404096   : E int    (4000000)
    //   h1     @ 6404096   : N*64 f32 (25600000)
    char* ws = (char*)d_ws;
    int*   deg    = (int*)(ws);
    int*   offs   = (int*)(ws + 800000);
    int*   cursor = (int*)(ws + 1600000);
    int*   bsum   = (int*)(ws + 2400000);
    int*   elist  = (int*)(ws + 2404096);
    float* h1     = (float*)(ws + 6404096);

    const int nblk_scan = (N2 + 255) / 256;        // 782
    const int grid_e    = (N_EDGES + 255) / 256;   // 3907
    const int grid_n    = N_NODES / 16;            // 6250 (16 waves/block)

    hipMemsetAsync(deg, 0, (size_t)N2 * 4, stream);
    k_count<<<grid_e, 256, 0, stream>>>(ei, ea, deg);
    k_scan_local<<<nblk_scan, 256, 0, stream>>>(deg, offs, bsum);
    k_scan_blocks<<<1, 64, 0, stream>>>(bsum, nblk_scan);
    k_scan_add<<<nblk_scan, 256, 0, stream>>>(offs, bsum, cursor);
    k_fill<<<grid_e, 256, 0, stream>>>(ei, ea, cursor, elist);

    k_fused1<<<grid_n, 1024, 0, stream>>>(x, offs, deg, elist, root1, W1, b1, h1);
    k_fused2<<<grid_n, 1024, 0, stream>>>(h1, offs, deg, elist, root2, W2, b2, Wc, bc, out);
}

// Round 5
// 517.986 us; speedup vs baseline: 3.5509x; 1.1409x over previous
//
#include <hip/hip_runtime.h>

#define N_NODES 100000
#define N_EDGES 1000000
#define IN_DIM 32
#define HID_DIM 64
#define N2 (2 * N_NODES)          // (rel,node) buckets
#define CHUNK 50000               // layer-2 mean chunking (2 passes)

// ============ CSR build: histogram -> scan -> fill ============

__global__ __launch_bounds__(256) void k_count(
    const int* __restrict__ ei, const int* __restrict__ ea,
    int* __restrict__ deg)
{
    int e = blockIdx.x * 256 + threadIdx.x;
    if (e >= N_EDGES) return;
    int dst = ei[N_EDGES + e];
    int rel = ea[2 * e + 1];
    atomicAdd(&deg[rel * N_NODES + dst], 1);
}

__global__ __launch_bounds__(256) void k_scan_local(
    const int* __restrict__ deg, int* __restrict__ offs, int* __restrict__ bsum)
{
    int t = threadIdx.x;
    int i = blockIdx.x * 256 + t;
    int v = (i < N2) ? deg[i] : 0;
    int lane = t & 63, w = t >> 6;
    int s = v;
#pragma unroll
    for (int off = 1; off < 64; off <<= 1) {
        int u = __shfl_up(s, off);
        if (lane >= off) s += u;
    }
    __shared__ int wsum[4];
    if (lane == 63) wsum[w] = s;
    __syncthreads();
    int add = 0;
    for (int ww = 0; ww < w; ++ww) add += wsum[ww];
    s += add;
    if (i < N2) offs[i] = s - v;                 // block-local exclusive
    if (t == 255) bsum[blockIdx.x] = s;          // block total
}

__global__ __launch_bounds__(64) void k_scan_blocks(int* __restrict__ bsum, int nblk)
{
    int lane = threadIdx.x;  // single wave
    int carry = 0;
    for (int base = 0; base < nblk; base += 64) {
        int i = base + lane;
        int v = (i < nblk) ? bsum[i] : 0;
        int s = v;
#pragma unroll
        for (int off = 1; off < 64; off <<= 1) {
            int u = __shfl_up(s, off);
            if (lane >= off) s += u;
        }
        if (i < nblk) bsum[i] = carry + s - v;   // exclusive
        carry += __shfl(s, 63);
    }
}

__global__ __launch_bounds__(256) void k_scan_add(
    int* __restrict__ offs, const int* __restrict__ bsum, int* __restrict__ cursor)
{
    int i = blockIdx.x * 256 + threadIdx.x;
    if (i >= N2) return;
    int o = offs[i] + bsum[i >> 8];
    offs[i] = o;
    cursor[i] = o;
}

__global__ __launch_bounds__(256) void k_fill(
    const int* __restrict__ ei, const int* __restrict__ ea,
    int* __restrict__ cursor, int* __restrict__ elist)
{
    int e = blockIdx.x * 256 + threadIdx.x;
    if (e >= N_EDGES) return;
    int src = ei[e];
    int dst = ei[N_EDGES + e];
    int rel = ea[2 * e + 1];
    int pos = atomicAdd(&cursor[rel * N_NODES + dst], 1);
    elist[pos] = src;
}

// ============ gather-mean kernels (no LDS arrays, ~1 bpermute/edge) ============
// Wave per node. Edge batch (<=64) preloaded into one lane register via a
// coalesced load; src indices broadcast with __shfl; row loads unrolled for
// MLP. Means are pre-divided and stored dense for uniform-float4 consumption
// by the register-blocked matmul kernels.

__global__ __launch_bounds__(256) void k_mean1(
    const float* __restrict__ x,      // [N][32]
    const int* __restrict__ offs,     // [2N]
    const int* __restrict__ deg,      // [2N]
    const int* __restrict__ elist,    // [E]
    float* __restrict__ M1)           // [2][N][32]
{
    int tid = threadIdx.x;
    int lane = tid & 63;
    int node = blockIdx.x * 4 + (tid >> 6);
    if (node >= N_NODES) return;
    int f = lane & 31, slot = lane >> 5;

    for (int r = 0; r < 2; ++r) {
        int b  = r * N_NODES + node;
        int s0 = offs[b];
        int d0 = deg[b];
        float aA = 0.0f, aB = 0.0f;
        for (int base = 0; base < d0; base += 64) {
            int nb = min(d0 - base, 64);
            int ereg = (lane < nb) ? elist[s0 + base + lane] : 0;
            int k = 0;
            for (; k + 4 <= nb; k += 4) {           // 2 rows/wave-step, x2 unroll
                int s1 = __shfl(ereg, k + slot);
                int s2 = __shfl(ereg, k + 2 + slot);
                aA += x[(size_t)s1 * IN_DIM + f];
                aB += x[(size_t)s2 * IN_DIM + f];
            }
            for (; k + 2 <= nb; k += 2) {
                int s1 = __shfl(ereg, k + slot);
                aA += x[(size_t)s1 * IN_DIM + f];
            }
            if (k < nb) {                            // odd tail: slot 0 only
                int s1 = __shfl(ereg, k);
                float v = x[(size_t)s1 * IN_DIM + f];
                aA += slot ? 0.0f : v;
            }
        }
        float a = aA + aB;
        a += __shfl_xor(a, 32);
        float m = a / fmaxf((float)d0, 1.0f);
        if (slot == 0)
            M1[((size_t)r * N_NODES + node) * IN_DIM + f] = m;
    }
}

__global__ __launch_bounds__(256) void k_mean2(
    const float* __restrict__ h1,     // [N][64]
    const int* __restrict__ offs,
    const int* __restrict__ deg,
    const int* __restrict__ elist,
    float* __restrict__ M2,           // [2][CHUNK][64]
    int c0)                           // chunk base node
{
    int tid = threadIdx.x;
    int lane = tid & 63;
    int node = c0 + blockIdx.x * 4 + (tid >> 6);
    if (node >= c0 + CHUNK || node >= N_NODES) return;

    for (int r = 0; r < 2; ++r) {
        int b  = r * N_NODES + node;
        int s0 = offs[b];
        int d0 = deg[b];
        float a0 = 0.0f, a1 = 0.0f, a2 = 0.0f, a3 = 0.0f;
        for (int base = 0; base < d0; base += 64) {
            int nb = min(d0 - base, 64);
            int ereg = (lane < nb) ? elist[s0 + base + lane] : 0;
            int k = 0;
            for (; k + 4 <= nb; k += 4) {            // 4 row loads in flight
                int sA = __shfl(ereg, k);
                int sB = __shfl(ereg, k + 1);
                int sC = __shfl(ereg, k + 2);
                int sD = __shfl(ereg, k + 3);
                a0 += h1[(size_t)sA * HID_DIM + lane];
                a1 += h1[(size_t)sB * HID_DIM + lane];
                a2 += h1[(size_t)sC * HID_DIM + lane];
                a3 += h1[(size_t)sD * HID_DIM + lane];
            }
            for (; k < nb; ++k) {
                int sA = __shfl(ereg, k);
                a0 += h1[(size_t)sA * HID_DIM + lane];
            }
        }
        float m = ((a0 + a1) + (a2 + a3)) / fmaxf((float)d0, 1.0f);
        M2[((size_t)r * CHUNK + (node - c0)) * HID_DIM + lane] = m;
    }
}

// ============ register-blocked matmul kernels (round-3 structure) ============
// 256 threads = 4 waves; lane = output feature j; 4 nodes register-blocked.
// Node rows (self + means) are wave-UNIFORM float4 global loads (L1 broadcast,
// no LDS pipe); weights from LDS, 12 reads amortized over 4 nodes.
// CRITICAL: kk loop must stay #pragma unroll 1 (full unroll spills -> 3.1 GB
// scratch traffic, rounds 0-2).

#define NODES_PER_BLOCK 64

#define ACC4(acc, v, wa, wb, wc_, wd) \
    acc = fmaf((v).x, wa, acc);       \
    acc = fmaf((v).y, wb, acc);       \
    acc = fmaf((v).z, wc_, acc);      \
    acc = fmaf((v).w, wd, acc);

__global__ __launch_bounds__(256, 4) void k_layer1(
    const float* __restrict__ x,      // [N][32]
    const float* __restrict__ M1,     // [2][N][32] (pre-divided means)
    const float* __restrict__ root1,  // [32][64]
    const float* __restrict__ W1,     // [2][32][64]
    const float* __restrict__ b1,     // [64]
    float* __restrict__ h1)           // [N][64]
{
    __shared__ float wR[IN_DIM * HID_DIM];
    __shared__ float w0[IN_DIM * HID_DIM];
    __shared__ float w1s[IN_DIM * HID_DIM];
    int tid = threadIdx.x;
    for (int i = tid; i < IN_DIM * HID_DIM; i += 256) {
        wR[i]  = root1[i];
        w0[i]  = W1[i];
        w1s[i] = W1[IN_DIM * HID_DIM + i];
    }
    __syncthreads();

    int j   = tid & 63;
    int sub = tid >> 6;
    float bj = b1[j];
    int base = blockIdx.x * NODES_PER_BLOCK;

    for (int it = 0; it < 4; ++it) {
        int n0 = base + it * 16 + sub * 4;
        if (n0 >= N_NODES) continue;

        float accR0 = 0, accR1 = 0, accR2 = 0, accR3 = 0;
        float acc00 = 0, acc01 = 0, acc02 = 0, acc03 = 0;
        float acc10 = 0, acc11 = 0, acc12 = 0, acc13 = 0;

#pragma unroll 1
        for (int kk = 0; kk < IN_DIM / 4; ++kk) {
            int kbase = kk * 4;
            float wRa = wR[(kbase + 0) * 64 + j];
            float wRb = wR[(kbase + 1) * 64 + j];
            float wRc = wR[(kbase + 2) * 64 + j];
            float wRd = wR[(kbase + 3) * 64 + j];
            float w0a = w0[(kbase + 0) * 64 + j];
            float w0b = w0[(kbase + 1) * 64 + j];
            float w0c = w0[(kbase + 2) * 64 + j];
            float w0d = w0[(kbase + 3) * 64 + j];
            float w1a = w1s[(kbase + 0) * 64 + j];
            float w1b = w1s[(kbase + 1) * 64 + j];
            float w1c = w1s[(kbase + 2) * 64 + j];
            float w1d = w1s[(kbase + 3) * 64 + j];

#define L1_NODE(i, accR, acc0, acc1)                                              \
            {                                                                     \
                size_t n = (size_t)(n0 + i);                                      \
                float4 xa = *(const float4*)(x  + n * IN_DIM + kbase);            \
                float4 q0 = *(const float4*)(M1 + n * IN_DIM + kbase);            \
                float4 q1 = *(const float4*)(M1 + ((size_t)N_NODES + n) * IN_DIM + kbase); \
                ACC4(accR, xa, wRa, wRb, wRc, wRd)                                \
                ACC4(acc0, q0, w0a, w0b, w0c, w0d)                                \
                ACC4(acc1, q1, w1a, w1b, w1c, w1d)                                \
            }
            L1_NODE(0, accR0, acc00, acc10)
            L1_NODE(1, accR1, acc01, acc11)
            L1_NODE(2, accR2, acc02, acc12)
            L1_NODE(3, accR3, acc03, acc13)
#undef L1_NODE
        }

#define L1_OUT(i, accR, acc0, acc1)                                               \
        {                                                                         \
            int n = n0 + i;                                                       \
            float o = accR + bj + acc0 + acc1;                                    \
            h1[(size_t)n * HID_DIM + j] = fmaxf(o, 0.0f);                         \
        }
        L1_OUT(0, accR0, acc00, acc10)
        L1_OUT(1, accR1, acc01, acc11)
        L1_OUT(2, accR2, acc02, acc12)
        L1_OUT(3, accR3, acc03, acc13)
#undef L1_OUT
    }
}

__global__ __launch_bounds__(256, 4) void k_layer2_cls(
    const float* __restrict__ h1,     // [N][64]
    const float* __restrict__ M2,     // [2][CHUNK][64]
    const float* __restrict__ root2,  // [64][64]
    const float* __restrict__ W2,     // [2][64][64]
    const float* __restrict__ b2,     // [64]
    const float* __restrict__ Wc,     // [64][2]
    const float* __restrict__ bc,     // [2]
    float* __restrict__ out,          // [N][2]
    int c0)
{
    __shared__ float wR[HID_DIM * HID_DIM];
    __shared__ float w0[HID_DIM * HID_DIM];
    __shared__ float w1s[HID_DIM * HID_DIM];
    __shared__ float wc[HID_DIM * 2];
    int tid = threadIdx.x;
    for (int i = tid; i < HID_DIM * HID_DIM; i += 256) {
        wR[i]  = root2[i];
        w0[i]  = W2[i];
        w1s[i] = W2[HID_DIM * HID_DIM + i];
    }
    if (tid < HID_DIM * 2) wc[tid] = Wc[tid];
    __syncthreads();

    int j   = tid & 63;
    int sub = tid >> 6;
    float bj  = b2[j];
    float bc0 = bc[0], bc1 = bc[1];
    int base = c0 + blockIdx.x * NODES_PER_BLOCK;
    int nend = c0 + CHUNK;

    for (int it = 0; it < 4; ++it) {
        int n0 = base + it * 16 + sub * 4;
        if (n0 >= nend) continue;

        float accR0 = 0, accR1 = 0, accR2 = 0, accR3 = 0;
        float acc00 = 0, acc01 = 0, acc02 = 0, acc03 = 0;
        float acc10 = 0, acc11 = 0, acc12 = 0, acc13 = 0;

#pragma unroll 1
        for (int kk = 0; kk < HID_DIM / 4; ++kk) {
            int kbase = kk * 4;
            float wRa = wR[(kbase + 0) * 64 + j];
            float wRb = wR[(kbase + 1) * 64 + j];
            float wRc = wR[(kbase + 2) * 64 + j];
            float wRd = wR[(kbase + 3) * 64 + j];
            float w0a = w0[(kbase + 0) * 64 + j];
            float w0b = w0[(kbase + 1) * 64 + j];
            float w0c = w0[(kbase + 2) * 64 + j];
            float w0d = w0[(kbase + 3) * 64 + j];
            float w1a = w1s[(kbase + 0) * 64 + j];
            float w1b = w1s[(kbase + 1) * 64 + j];
            float w1c = w1s[(kbase + 2) * 64 + j];
            float w1d = w1s[(kbase + 3) * 64 + j];

#define L2_NODE(i, accR, acc0, acc1)                                              \
            {                                                                     \
                size_t n = (size_t)(n0 + i);                                      \
                size_t c = n - c0;                                                \
                float4 xa = *(const float4*)(h1 + n * HID_DIM + kbase);           \
                float4 q0 = *(const float4*)(M2 + c * HID_DIM + kbase);           \
                float4 q1 = *(const float4*)(M2 + ((size_t)CHUNK + c) * HID_DIM + kbase); \
                ACC4(accR, xa, wRa, wRb, wRc, wRd)                                \
                ACC4(acc0, q0, w0a, w0b, w0c, w0d)                                \
                ACC4(acc1, q1, w1a, w1b, w1c, w1d)                                \
            }
            L2_NODE(0, accR0, acc00, acc10)
            L2_NODE(1, accR1, acc01, acc11)
            L2_NODE(2, accR2, acc02, acc12)
            L2_NODE(3, accR3, acc03, acc13)
#undef L2_NODE
        }

#define L2_OUT(i, accR, acc0, acc1)                                               \
        {                                                                         \
            int n = n0 + i;                                                       \
            float h2 = fmaxf(accR + bj + acc0 + acc1, 0.0f);                      \
            float v0 = h2 * wc[2 * j];                                            \
            float v1 = h2 * wc[2 * j + 1];                                        \
            for (int off = 32; off >= 1; off >>= 1) {                             \
                v0 += __shfl_xor(v0, off);                                        \
                v1 += __shfl_xor(v1, off);                                        \
            }                                                                     \
            if (j == 0) {                                                         \
                out[(size_t)n * 2 + 0] = v0 + bc0;                                \
                out[(size_t)n * 2 + 1] = v1 + bc1;                                \
            }                                                                     \
        }
        L2_OUT(0, accR0, acc00, acc10)
        L2_OUT(1, accR1, acc01, acc11)
        L2_OUT(2, accR2, acc02, acc12)
        L2_OUT(3, accR3, acc03, acc13)
#undef L2_OUT
    }
}

// ============ launch ============

extern "C" void kernel_launch(void* const* d_in, const int* in_sizes, int n_in,
                              void* d_out, int out_size, void* d_ws, size_t ws_size,
                              hipStream_t stream) {
    const float* x     = (const float*)d_in[0];
    const int*   ei    = (const int*)d_in[1];
    const int*   ea    = (const int*)d_in[2];
    const float* W1    = (const float*)d_in[3];
    const float* root1 = (const float*)d_in[4];
    const float* b1    = (const float*)d_in[5];
    const float* W2    = (const float*)d_in[6];
    const float* root2 = (const float*)d_in[7];
    const float* b2    = (const float*)d_in[8];
    const float* Wc    = (const float*)d_in[9];
    const float* bc    = (const float*)d_in[10];
    float* out = (float*)d_out;

    // ws layout (bytes), peak 56.8 MB (proven budget >= 77.6 MB):
    //   deg   @ 0        : 2N int (800000)
    //   offs  @ 800000   : 2N int (800000)
    //   elist @ 1600000  : E int  (4000000)
    //   h1    @ 5600000  : N*64 f32 (25600000)
    //   MB    @ 31200000 : 25.6 MB, time-shared:
    //     CSR build: cursor (2N int) + bsum (1024 int) live here
    //     then M1 [2][N][32] f32; then M2 [2][CHUNK][64] f32 per chunk
    char* ws = (char*)d_ws;
    int*   deg    = (int*)(ws);
    int*   offs   = (int*)(ws + 800000);
    int*   elist  = (int*)(ws + 1600000);
    float* h1     = (float*)(ws + 5600000);
    char*  MB     = ws + 31200000;
    int*   cursor = (int*)(MB);
    int*   bsum   = (int*)(MB + 800000);
    float* M1     = (float*)(MB);
    float* M2     = (float*)(MB);

    const int nblk_scan = (N2 + 255) / 256;        // 782
    const int grid_e    = (N_EDGES + 255) / 256;   // 3907

    hipMemsetAsync(deg, 0, (size_t)N2 * 4, stream);
    k_count<<<grid_e, 256, 0, stream>>>(ei, ea, deg);
    k_scan_local<<<nblk_scan, 256, 0, stream>>>(deg, offs, bsum);
    k_scan_blocks<<<1, 64, 0, stream>>>(bsum, nblk_scan);
    k_scan_add<<<nblk_scan, 256, 0, stream>>>(offs, bsum, cursor);
    k_fill<<<grid_e, 256, 0, stream>>>(ei, ea, cursor, elist);

    // layer 1: means then register-blocked matmul
    k_mean1<<<N_NODES / 4, 256, 0, stream>>>(x, offs, deg, elist, M1);
    k_layer1<<<(N_NODES + NODES_PER_BLOCK - 1) / NODES_PER_BLOCK, 256, 0, stream>>>(
        x, M1, root1, W1, b1, h1);

    // layer 2 + classifier, chunked so M2 fits the MB region
    const int grid_c = (CHUNK + NODES_PER_BLOCK - 1) / NODES_PER_BLOCK;  // 782
    for (int c = 0; c < 2; ++c) {
        int c0 = c * CHUNK;
        k_mean2<<<CHUNK / 4, 256, 0, stream>>>(h1, offs, deg, elist, M2, c0);
        k_layer2_cls<<<grid_c, 256, 0, stream>>>(h1, M2, root2, W2, b2, Wc, bc, out, c0);
    }
}

// Round 6
// 414.284 us; speedup vs baseline: 4.4397x; 1.2503x over previous
//
#include <hip/hip_runtime.h>

#define N_NODES 100000
#define N_EDGES 1000000
#define IN_DIM 32
#define HID_DIM 64
#define N2 (2 * N_NODES)          // (rel,node) buckets
#define CHUNK 50000               // layer-2 mean chunking (2 passes)

// ============ CSR build: histogram -> scan -> fill ============

__global__ __launch_bounds__(256) void k_count(
    const int* __restrict__ ei, const int* __restrict__ ea,
    int* __restrict__ deg)
{
    int e = blockIdx.x * 256 + threadIdx.x;
    if (e >= N_EDGES) return;
    int dst = ei[N_EDGES + e];
    int rel = ea[2 * e + 1];
    atomicAdd(&deg[rel * N_NODES + dst], 1);
}

__global__ __launch_bounds__(256) void k_scan_local(
    const int* __restrict__ deg, int* __restrict__ offs, int* __restrict__ bsum)
{
    int t = threadIdx.x;
    int i = blockIdx.x * 256 + t;
    int v = (i < N2) ? deg[i] : 0;
    int lane = t & 63, w = t >> 6;
    int s = v;
#pragma unroll
    for (int off = 1; off < 64; off <<= 1) {
        int u = __shfl_up(s, off);
        if (lane >= off) s += u;
    }
    __shared__ int wsum[4];
    if (lane == 63) wsum[w] = s;
    __syncthreads();
    int add = 0;
    for (int ww = 0; ww < w; ++ww) add += wsum[ww];
    s += add;
    if (i < N2) offs[i] = s - v;                 // block-local exclusive
    if (t == 255) bsum[blockIdx.x] = s;          // block total
}

__global__ __launch_bounds__(64) void k_scan_blocks(int* __restrict__ bsum, int nblk)
{
    int lane = threadIdx.x;  // single wave
    int carry = 0;
    for (int base = 0; base < nblk; base += 64) {
        int i = base + lane;
        int v = (i < nblk) ? bsum[i] : 0;
        int s = v;
#pragma unroll
        for (int off = 1; off < 64; off <<= 1) {
            int u = __shfl_up(s, off);
            if (lane >= off) s += u;
        }
        if (i < nblk) bsum[i] = carry + s - v;   // exclusive
        carry += __shfl(s, 63);
    }
}

__global__ __launch_bounds__(256) void k_scan_add(
    int* __restrict__ offs, const int* __restrict__ bsum, int* __restrict__ cursor)
{
    int i = blockIdx.x * 256 + threadIdx.x;
    if (i >= N2) return;
    int o = offs[i] + bsum[i >> 8];
    offs[i] = o;
    cursor[i] = o;
}

__global__ __launch_bounds__(256) void k_fill(
    const int* __restrict__ ei, const int* __restrict__ ea,
    int* __restrict__ cursor, int* __restrict__ elist)
{
    int e = blockIdx.x * 256 + threadIdx.x;
    if (e >= N_EDGES) return;
    int src = ei[e];
    int dst = ei[N_EDGES + e];
    int rel = ea[2 * e + 1];
    int pos = atomicAdd(&cursor[rel * N_NODES + dst], 1);
    elist[pos] = src;
}

// ============ gather-mean kernels ============
// Wave per node. Edge batch (<=64) preloaded into one lane register; src
// indices broadcast with __shfl; row loads unrolled deep for MLP. Means
// pre-divided, stored dense for uniform-float4 consumption by matmuls.

__global__ __launch_bounds__(256) void k_mean1(
    const float* __restrict__ x,      // [N][32]
    const int* __restrict__ offs,     // [2N]
    const int* __restrict__ deg,      // [2N]
    const int* __restrict__ elist,    // [E]
    float* __restrict__ M1)           // [2][N][32]
{
    int tid = threadIdx.x;
    int lane = tid & 63;
    int node = blockIdx.x * 4 + (tid >> 6);
    if (node >= N_NODES) return;
    int f = lane & 31, slot = lane >> 5;

    for (int r = 0; r < 2; ++r) {
        int b  = r * N_NODES + node;
        int s0 = offs[b];
        int d0 = deg[b];
        float a1 = 0.0f, a2 = 0.0f, a3 = 0.0f, a4 = 0.0f;
        for (int base = 0; base < d0; base += 64) {
            int nb = min(d0 - base, 64);
            int ereg = (lane < nb) ? elist[s0 + base + lane] : 0;
            int k = 0;
            for (; k + 8 <= nb; k += 8) {           // 8 rows per wave step
                int sA = __shfl(ereg, k + slot);
                int sB = __shfl(ereg, k + 2 + slot);
                int sC = __shfl(ereg, k + 4 + slot);
                int sD = __shfl(ereg, k + 6 + slot);
                a1 += x[(size_t)sA * IN_DIM + f];
                a2 += x[(size_t)sB * IN_DIM + f];
                a3 += x[(size_t)sC * IN_DIM + f];
                a4 += x[(size_t)sD * IN_DIM + f];
            }
            for (; k + 2 <= nb; k += 2) {
                int sA = __shfl(ereg, k + slot);
                a1 += x[(size_t)sA * IN_DIM + f];
            }
            if (k < nb) {                            // odd tail: slot 0 only
                int sA = __shfl(ereg, k);
                float v = x[(size_t)sA * IN_DIM + f];
                a1 += slot ? 0.0f : v;
            }
        }
        float a = (a1 + a2) + (a3 + a4);
        a += __shfl_xor(a, 32);
        float m = a / fmaxf((float)d0, 1.0f);
        if (slot == 0)
            M1[((size_t)r * N_NODES + node) * IN_DIM + f] = m;
    }
}

__global__ __launch_bounds__(256) void k_mean2(
    const float* __restrict__ h1,     // [N][64]
    const int* __restrict__ offs,
    const int* __restrict__ deg,
    const int* __restrict__ elist,
    float* __restrict__ M2,           // [2][CHUNK][64]
    int c0)                           // chunk base node
{
    int tid = threadIdx.x;
    int lane = tid & 63;
    int node = c0 + blockIdx.x * 4 + (tid >> 6);
    if (node >= c0 + CHUNK || node >= N_NODES) return;

    for (int r = 0; r < 2; ++r) {
        int b  = r * N_NODES + node;
        int s0 = offs[b];
        int d0 = deg[b];
        float a0 = 0.0f, a1 = 0.0f, a2 = 0.0f, a3 = 0.0f;
        float a4 = 0.0f, a5 = 0.0f, a6 = 0.0f, a7 = 0.0f;
        for (int base = 0; base < d0; base += 64) {
            int nb = min(d0 - base, 64);
            int ereg = (lane < nb) ? elist[s0 + base + lane] : 0;
            int k = 0;
            for (; k + 8 <= nb; k += 8) {            // 8 row loads in flight
                int sA = __shfl(ereg, k);
                int sB = __shfl(ereg, k + 1);
                int sC = __shfl(ereg, k + 2);
                int sD = __shfl(ereg, k + 3);
                int sE = __shfl(ereg, k + 4);
                int sF = __shfl(ereg, k + 5);
                int sG = __shfl(ereg, k + 6);
                int sH = __shfl(ereg, k + 7);
                a0 += h1[(size_t)sA * HID_DIM + lane];
                a1 += h1[(size_t)sB * HID_DIM + lane];
                a2 += h1[(size_t)sC * HID_DIM + lane];
                a3 += h1[(size_t)sD * HID_DIM + lane];
                a4 += h1[(size_t)sE * HID_DIM + lane];
                a5 += h1[(size_t)sF * HID_DIM + lane];
                a6 += h1[(size_t)sG * HID_DIM + lane];
                a7 += h1[(size_t)sH * HID_DIM + lane];
            }
            for (; k + 4 <= nb; k += 4) {
                int sA = __shfl(ereg, k);
                int sB = __shfl(ereg, k + 1);
                int sC = __shfl(ereg, k + 2);
                int sD = __shfl(ereg, k + 3);
                a0 += h1[(size_t)sA * HID_DIM + lane];
                a1 += h1[(size_t)sB * HID_DIM + lane];
                a2 += h1[(size_t)sC * HID_DIM + lane];
                a3 += h1[(size_t)sD * HID_DIM + lane];
            }
            for (; k < nb; ++k) {
                int sA = __shfl(ereg, k);
                a0 += h1[(size_t)sA * HID_DIM + lane];
            }
        }
        float m = (((a0 + a1) + (a2 + a3)) + ((a4 + a5) + (a6 + a7)))
                  / fmaxf((float)d0, 1.0f);
        M2[((size_t)r * CHUNK + (node - c0)) * HID_DIM + lane] = m;
    }
}

// ============ register-blocked matmul kernels ============
// 512 threads = 8 waves; lane = output feature j; 4 nodes register-blocked;
// 32 nodes/block, no outer loop. Register-LEAN inner loop (one matrix at a
// time: 4 weights + 4 float4 live) + __launch_bounds__(512,8) targets
// VGPR <= 64 so occupancy is LDS-capped (layer2: 3 blk x 8 = 24 waves/CU),
// fixing round-5's latency-bound 22% occupancy.
// CRITICAL: kk loop stays #pragma unroll 1 (full unroll spills -> 3.1 GB
// scratch traffic, rounds 0-2).

#define ACC4(acc, v, wa, wb, wc_, wd) \
    acc = fmaf((v).x, wa, acc);       \
    acc = fmaf((v).y, wb, acc);       \
    acc = fmaf((v).z, wc_, acc);      \
    acc = fmaf((v).w, wd, acc);

__global__ __launch_bounds__(512, 8) void k_layer1(
    const float* __restrict__ x,      // [N][32]
    const float* __restrict__ M1,     // [2][N][32] (pre-divided means)
    const float* __restrict__ root1,  // [32][64]
    const float* __restrict__ W1,     // [2][32][64]
    const float* __restrict__ b1,     // [64]
    float* __restrict__ h1)           // [N][64]
{
    __shared__ float wR[IN_DIM * HID_DIM];
    __shared__ float w0[IN_DIM * HID_DIM];
    __shared__ float w1s[IN_DIM * HID_DIM];
    int tid = threadIdx.x;
    for (int i = tid; i < IN_DIM * HID_DIM; i += 512) {
        wR[i]  = root1[i];
        w0[i]  = W1[i];
        w1s[i] = W1[IN_DIM * HID_DIM + i];
    }
    __syncthreads();

    int j  = tid & 63;
    int n0 = __builtin_amdgcn_readfirstlane(blockIdx.x * 32 + (tid >> 6) * 4);
    if (n0 >= N_NODES) return;   // 32 | 100000 -> never taken, kept for safety

    const float* px = x  + (size_t)n0 * IN_DIM;
    const float* p0 = M1 + (size_t)n0 * IN_DIM;
    const float* p1 = M1 + ((size_t)N_NODES + n0) * IN_DIM;

    float accR0 = 0, accR1 = 0, accR2 = 0, accR3 = 0;
    float acc00 = 0, acc01 = 0, acc02 = 0, acc03 = 0;
    float acc10 = 0, acc11 = 0, acc12 = 0, acc13 = 0;

#pragma unroll 1
    for (int kk = 0; kk < IN_DIM / 4; ++kk) {
        int kbase = kk * 4;
        int wb_i  = kbase * 64 + j;
        {   // self @ root1
            float wa = wR[wb_i], wb = wR[wb_i + 64], wc_ = wR[wb_i + 128], wd = wR[wb_i + 192];
            float4 v0 = *(const float4*)(px + 0 * IN_DIM + kbase);
            float4 v1 = *(const float4*)(px + 1 * IN_DIM + kbase);
            float4 v2 = *(const float4*)(px + 2 * IN_DIM + kbase);
            float4 v3 = *(const float4*)(px + 3 * IN_DIM + kbase);
            ACC4(accR0, v0, wa, wb, wc_, wd)
            ACC4(accR1, v1, wa, wb, wc_, wd)
            ACC4(accR2, v2, wa, wb, wc_, wd)
            ACC4(accR3, v3, wa, wb, wc_, wd)
        }
        {   // mean rel0 @ W1[0]
            float wa = w0[wb_i], wb = w0[wb_i + 64], wc_ = w0[wb_i + 128], wd = w0[wb_i + 192];
            float4 v0 = *(const float4*)(p0 + 0 * IN_DIM + kbase);
            float4 v1 = *(const float4*)(p0 + 1 * IN_DIM + kbase);
            float4 v2 = *(const float4*)(p0 + 2 * IN_DIM + kbase);
            float4 v3 = *(const float4*)(p0 + 3 * IN_DIM + kbase);
            ACC4(acc00, v0, wa, wb, wc_, wd)
            ACC4(acc01, v1, wa, wb, wc_, wd)
            ACC4(acc02, v2, wa, wb, wc_, wd)
            ACC4(acc03, v3, wa, wb, wc_, wd)
        }
        {   // mean rel1 @ W1[1]
            float wa = w1s[wb_i], wb = w1s[wb_i + 64], wc_ = w1s[wb_i + 128], wd = w1s[wb_i + 192];
            float4 v0 = *(const float4*)(p1 + 0 * IN_DIM + kbase);
            float4 v1 = *(const float4*)(p1 + 1 * IN_DIM + kbase);
            float4 v2 = *(const float4*)(p1 + 2 * IN_DIM + kbase);
            float4 v3 = *(const float4*)(p1 + 3 * IN_DIM + kbase);
            ACC4(acc10, v0, wa, wb, wc_, wd)
            ACC4(acc11, v1, wa, wb, wc_, wd)
            ACC4(acc12, v2, wa, wb, wc_, wd)
            ACC4(acc13, v3, wa, wb, wc_, wd)
        }
    }

    float bj = b1[j];
    h1[(size_t)(n0 + 0) * HID_DIM + j] = fmaxf(accR0 + bj + acc00 + acc10, 0.0f);
    h1[(size_t)(n0 + 1) * HID_DIM + j] = fmaxf(accR1 + bj + acc01 + acc11, 0.0f);
    h1[(size_t)(n0 + 2) * HID_DIM + j] = fmaxf(accR2 + bj + acc02 + acc12, 0.0f);
    h1[(size_t)(n0 + 3) * HID_DIM + j] = fmaxf(accR3 + bj + acc03 + acc13, 0.0f);
}

__global__ __launch_bounds__(512, 8) void k_layer2_cls(
    const float* __restrict__ h1,     // [N][64]
    const float* __restrict__ M2,     // [2][CHUNK][64]
    const float* __restrict__ root2,  // [64][64]
    const float* __restrict__ W2,     // [2][64][64]
    const float* __restrict__ b2,     // [64]
    const float* __restrict__ Wc,     // [64][2]
    const float* __restrict__ bc,     // [2]
    float* __restrict__ out,          // [N][2]
    int c0)
{
    __shared__ float wR[HID_DIM * HID_DIM];
    __shared__ float w0[HID_DIM * HID_DIM];
    __shared__ float w1s[HID_DIM * HID_DIM];
    __shared__ float wc[HID_DIM * 2];
    int tid = threadIdx.x;
    for (int i = tid; i < HID_DIM * HID_DIM; i += 512) {
        wR[i]  = root2[i];
        w0[i]  = W2[i];
        w1s[i] = W2[HID_DIM * HID_DIM + i];
    }
    if (tid < HID_DIM * 2) wc[tid] = Wc[tid];
    __syncthreads();

    int j  = tid & 63;
    int n0 = __builtin_amdgcn_readfirstlane(c0 + blockIdx.x * 32 + (tid >> 6) * 4);
    if (n0 >= c0 + CHUNK || n0 >= N_NODES) return;
    size_t cc = (size_t)(n0 - c0);

    const float* px = h1 + (size_t)n0 * HID_DIM;
    const float* p0 = M2 + cc * HID_DIM;
    const float* p1 = M2 + ((size_t)CHUNK + cc) * HID_DIM;

    float accR0 = 0, accR1 = 0, accR2 = 0, accR3 = 0;
    float acc00 = 0, acc01 = 0, acc02 = 0, acc03 = 0;
    float acc10 = 0, acc11 = 0, acc12 = 0, acc13 = 0;

#pragma unroll 1
    for (int kk = 0; kk < HID_DIM / 4; ++kk) {
        int kbase = kk * 4;
        int wb_i  = kbase * 64 + j;
        {
            float wa = wR[wb_i], wb = wR[wb_i + 64], wc_ = wR[wb_i + 128], wd = wR[wb_i + 192];
            float4 v0 = *(const float4*)(px + 0 * HID_DIM + kbase);
            float4 v1 = *(const float4*)(px + 1 * HID_DIM + kbase);
            float4 v2 = *(const float4*)(px + 2 * HID_DIM + kbase);
            float4 v3 = *(const float4*)(px + 3 * HID_DIM + kbase);
            ACC4(accR0, v0, wa, wb, wc_, wd)
            ACC4(accR1, v1, wa, wb, wc_, wd)
            ACC4(accR2, v2, wa, wb, wc_, wd)
            ACC4(accR3, v3, wa, wb, wc_, wd)
        }
        {
            float wa = w0[wb_i], wb = w0[wb_i + 64], wc_ = w0[wb_i + 128], wd = w0[wb_i + 192];
            float4 v0 = *(const float4*)(p0 + 0 * HID_DIM + kbase);
            float4 v1 = *(const float4*)(p0 + 1 * HID_DIM + kbase);
            float4 v2 = *(const float4*)(p0 + 2 * HID_DIM + kbase);
            float4 v3 = *(const float4*)(p0 + 3 * HID_DIM + kbase);
            ACC4(acc00, v0, wa, wb, wc_, wd)
            ACC4(acc01, v1, wa, wb, wc_, wd)
            ACC4(acc02, v2, wa, wb, wc_, wd)
            ACC4(acc03, v3, wa, wb, wc_, wd)
        }
        {
            float wa = w1s[wb_i], wb = w1s[wb_i + 64], wc_ = w1s[wb_i + 128], wd = w1s[wb_i + 192];
            float4 v0 = *(const float4*)(p1 + 0 * HID_DIM + kbase);
            float4 v1 = *(const float4*)(p1 + 1 * HID_DIM + kbase);
            float4 v2 = *(const float4*)(p1 + 2 * HID_DIM + kbase);
            float4 v3 = *(const float4*)(p1 + 3 * HID_DIM + kbase);
            ACC4(acc10, v0, wa, wb, wc_, wd)
            ACC4(acc11, v1, wa, wb, wc_, wd)
            ACC4(acc12, v2, wa, wb, wc_, wd)
            ACC4(acc13, v3, wa, wb, wc_, wd)
        }
    }

    float bj  = b2[j];
    float wcj0 = wc[2 * j], wcj1 = wc[2 * j + 1];
    float bc0 = bc[0], bc1 = bc[1];

#define L2_OUT(i, accR, acc0, acc1)                                           \
    {                                                                         \
        int n = n0 + i;                                                       \
        float h2 = fmaxf(accR + bj + acc0 + acc1, 0.0f);                      \
        float v0 = h2 * wcj0;                                                 \
        float v1 = h2 * wcj1;                                                 \
        for (int off = 32; off >= 1; off >>= 1) {                             \
            v0 += __shfl_xor(v0, off);                                        \
            v1 += __shfl_xor(v1, off);                                        \
        }                                                                     \
        if (j == 0) {                                                         \
            out[(size_t)n * 2 + 0] = v0 + bc0;                                \
            out[(size_t)n * 2 + 1] = v1 + bc1;                                \
        }                                                                     \
    }
    L2_OUT(0, accR0, acc00, acc10)
    L2_OUT(1, accR1, acc01, acc11)
    L2_OUT(2, accR2, acc02, acc12)
    L2_OUT(3, accR3, acc03, acc13)
#undef L2_OUT
}

// ============ launch ============

extern "C" void kernel_launch(void* const* d_in, const int* in_sizes, int n_in,
                              void* d_out, int out_size, void* d_ws, size_t ws_size,
                              hipStream_t stream) {
    const float* x     = (const float*)d_in[0];
    const int*   ei    = (const int*)d_in[1];
    const int*   ea    = (const int*)d_in[2];
    const float* W1    = (const float*)d_in[3];
    const float* root1 = (const float*)d_in[4];
    const float* b1    = (const float*)d_in[5];
    const float* W2    = (const float*)d_in[6];
    const float* root2 = (const float*)d_in[7];
    const float* b2    = (const float*)d_in[8];
    const float* Wc    = (const float*)d_in[9];
    const float* bc    = (const float*)d_in[10];
    float* out = (float*)d_out;

    // ws layout (bytes), peak 56.8 MB (proven budget >= 77.6 MB):
    //   deg   @ 0        : 2N int (800000)
    //   offs  @ 800000   : 2N int (800000)
    //   elist @ 1600000  : E int  (4000000)
    //   h1    @ 5600000  : N*64 f32 (25600000)
    //   MB    @ 31200000 : 25.6 MB, time-shared:
    //     CSR build: cursor (2N int) + bsum (1024 int) live here
    //     then M1 [2][N][32] f32; then M2 [2][CHUNK][64] f32 per chunk
    char* ws = (char*)d_ws;
    int*   deg    = (int*)(ws);
    int*   offs   = (int*)(ws + 800000);
    int*   elist  = (int*)(ws + 1600000);
    float* h1     = (float*)(ws + 5600000);
    char*  MB     = ws + 31200000;
    int*   cursor = (int*)(MB);
    int*   bsum   = (int*)(MB + 800000);
    float* M1     = (float*)(MB);
    float* M2     = (float*)(MB);

    const int nblk_scan = (N2 + 255) / 256;        // 782
    const int grid_e    = (N_EDGES + 255) / 256;   // 3907

    hipMemsetAsync(deg, 0, (size_t)N2 * 4, stream);
    k_count<<<grid_e, 256, 0, stream>>>(ei, ea, deg);
    k_scan_local<<<nblk_scan, 256, 0, stream>>>(deg, offs, bsum);
    k_scan_blocks<<<1, 64, 0, stream>>>(bsum, nblk_scan);
    k_scan_add<<<nblk_scan, 256, 0, stream>>>(offs, bsum, cursor);
    k_fill<<<grid_e, 256, 0, stream>>>(ei, ea, cursor, elist);

    // layer 1: means then register-blocked matmul (32 nodes/block)
    k_mean1<<<N_NODES / 4, 256, 0, stream>>>(x, offs, deg, elist, M1);
    k_layer1<<<N_NODES / 32, 512, 0, stream>>>(x, M1, root1, W1, b1, h1);

    // layer 2 + classifier, chunked so M2 fits the MB region
    const int grid_c = (CHUNK + 31) / 32;          // 1563
    for (int c = 0; c < 2; ++c) {
        int c0 = c * CHUNK;
        k_mean2<<<CHUNK / 4, 256, 0, stream>>>(h1, offs, deg, elist, M2, c0);
        k_layer2_cls<<<grid_c, 512, 0, stream>>>(h1, M2, root2, W2, b2, Wc, bc, out, c0);
    }
}

// Round 7
// 367.306 us; speedup vs baseline: 5.0075x; 1.1279x over previous
//
#include <hip/hip_runtime.h>

#define N_NODES 100000
#define N_EDGES 1000000
#define IN_DIM 32
#define HID_DIM 64
#define N2 (2 * N_NODES)          // (rel,node) buckets
#define CHUNK 50000               // layer-2 mean chunking (2 passes)
#define NRANGE 8                  // dst ranges == XCD count
#define RNODES (N_NODES / NRANGE) // 12500
#define ECHUNK 2048               // edges per block-chunk in count/fill

// ============ CSR build: XCD-local histogram -> scan -> XCD-local fill ============
// Blocks come in (chunk, range) pairs: range = blockIdx&7 tracks the XCD the
// block lands on (round-robin dispatch). Each block only touches deg/cursor/
// elist entries of its dst-range, so atomics and scatter writes stay in one
// XCD's L2 -- no cross-XCD cache-line migration (round-6: 70 MB write thrash).

__global__ __launch_bounds__(256) void k_count(
    const int* __restrict__ ei, const int* __restrict__ ea,
    int* __restrict__ deg)
{
    int range = blockIdx.x & (NRANGE - 1);
    int chunk = blockIdx.x >> 3;
    int lo = range * RNODES;
    int e0 = chunk * ECHUNK;
    int e1 = min(e0 + ECHUNK, N_EDGES);
    for (int e = e0 + threadIdx.x; e < e1; e += 256) {
        int dst = ei[N_EDGES + e];
        if ((unsigned)(dst - lo) < (unsigned)RNODES) {
            int rel = ea[2 * e + 1];
            atomicAdd(&deg[rel * N_NODES + dst], 1);
        }
    }
}

__global__ __launch_bounds__(256) void k_scan_local(
    const int* __restrict__ deg, int* __restrict__ offs, int* __restrict__ bsum)
{
    int t = threadIdx.x;
    int i = blockIdx.x * 256 + t;
    int v = (i < N2) ? deg[i] : 0;
    int lane = t & 63, w = t >> 6;
    int s = v;
#pragma unroll
    for (int off = 1; off < 64; off <<= 1) {
        int u = __shfl_up(s, off);
        if (lane >= off) s += u;
    }
    __shared__ int wsum[4];
    if (lane == 63) wsum[w] = s;
    __syncthreads();
    int add = 0;
    for (int ww = 0; ww < w; ++ww) add += wsum[ww];
    s += add;
    if (i < N2) offs[i] = s - v;                 // block-local exclusive
    if (t == 255) bsum[blockIdx.x] = s;          // block total
}

__global__ __launch_bounds__(64) void k_scan_blocks(int* __restrict__ bsum, int nblk)
{
    int lane = threadIdx.x;  // single wave
    int carry = 0;
    for (int base = 0; base < nblk; base += 64) {
        int i = base + lane;
        int v = (i < nblk) ? bsum[i] : 0;
        int s = v;
#pragma unroll
        for (int off = 1; off < 64; off <<= 1) {
            int u = __shfl_up(s, off);
            if (lane >= off) s += u;
        }
        if (i < nblk) bsum[i] = carry + s - v;   // exclusive
        carry += __shfl(s, 63);
    }
}

__global__ __launch_bounds__(256) void k_scan_add(
    const int* __restrict__ offs, const int* __restrict__ bsum,
    const int* __restrict__ deg,
    int* __restrict__ cursor, int2* __restrict__ od)
{
    int i = blockIdx.x * 256 + threadIdx.x;
    if (i >= N2) return;
    int o = offs[i] + bsum[i >> 8];
    cursor[i] = o;
    od[i] = make_int2(o, deg[i]);   // packed (off,deg): 1 load per rel in means
}

__global__ __launch_bounds__(256) void k_fill(
    const int* __restrict__ ei, const int* __restrict__ ea,
    int* __restrict__ cursor, int* __restrict__ elist)
{
    int range = blockIdx.x & (NRANGE - 1);
    int chunk = blockIdx.x >> 3;
    int lo = range * RNODES;
    int e0 = chunk * ECHUNK;
    int e1 = min(e0 + ECHUNK, N_EDGES);
    for (int e = e0 + threadIdx.x; e < e1; e += 256) {
        int dst = ei[N_EDGES + e];
        if ((unsigned)(dst - lo) < (unsigned)RNODES) {
            int rel = ea[2 * e + 1];
            int src = ei[e];
            int pos = atomicAdd(&cursor[rel * N_NODES + dst], 1);
            elist[pos] = src;
        }
    }
}

// ============ gather-mean kernels ============
// Wave per node. BOTH relations interleaved (independent load chains) with
// predicated row loads; edge batches preloaded up front. Common path d<=64
// (degree ~Poisson(5)); rare d>64 handled by a per-rel tail loop. Means are
// pre-divided and stored dense for uniform-float4 consumption by matmuls.

__global__ __launch_bounds__(256) void k_mean1(
    const float* __restrict__ x,      // [N][32]
    const int2* __restrict__ od,      // [2N] (off,deg)
    const int* __restrict__ elist,    // [E]
    float* __restrict__ M1)           // [2][N][32]
{
    int tid = threadIdx.x;
    int lane = tid & 63;
    int node = blockIdx.x * 4 + (tid >> 6);
    if (node >= N_NODES) return;
    int f = lane & 31, slot = lane >> 5;

    int2 o0 = od[node];
    int2 o1 = od[N_NODES + node];
    int d0 = o0.y, d1 = o1.y;
    int c0 = min(d0, 64), c1 = min(d1, 64);

    int e0r = (lane < c0) ? elist[o0.x + lane] : 0;
    int e1r = (lane < c1) ? elist[o1.x + lane] : 0;

    float a0 = 0, a1 = 0, a2 = 0, a3 = 0;
    int dmax = max(c0, c1);
    for (int k = 0; k < dmax; k += 4) {
        int s00 = __shfl(e0r, k + slot);
        int s01 = __shfl(e0r, k + 2 + slot);
        int s10 = __shfl(e1r, k + slot);
        int s11 = __shfl(e1r, k + 2 + slot);
        a0 += (k + slot     < c0) ? x[(size_t)s00 * IN_DIM + f] : 0.0f;
        a1 += (k + 2 + slot < c0) ? x[(size_t)s01 * IN_DIM + f] : 0.0f;
        a2 += (k + slot     < c1) ? x[(size_t)s10 * IN_DIM + f] : 0.0f;
        a3 += (k + 2 + slot < c1) ? x[(size_t)s11 * IN_DIM + f] : 0.0f;
    }
    if (d0 > 64) {                               // rare tail, rel 0
        for (int base = 64; base < d0; base += 64) {
            int nb = min(d0 - base, 64);
            int er = (lane < nb) ? elist[o0.x + base + lane] : 0;
            for (int k = 0; k < nb; k += 2) {
                int s = __shfl(er, k + slot);
                a0 += (k + slot < nb) ? x[(size_t)s * IN_DIM + f] : 0.0f;
            }
        }
    }
    if (d1 > 64) {                               // rare tail, rel 1
        for (int base = 64; base < d1; base += 64) {
            int nb = min(d1 - base, 64);
            int er = (lane < nb) ? elist[o1.x + base + lane] : 0;
            for (int k = 0; k < nb; k += 2) {
                int s = __shfl(er, k + slot);
                a2 += (k + slot < nb) ? x[(size_t)s * IN_DIM + f] : 0.0f;
            }
        }
    }

    float s0 = a0 + a1; s0 += __shfl_xor(s0, 32);
    float s1 = a2 + a3; s1 += __shfl_xor(s1, 32);
    if (slot == 0) {
        M1[(size_t)node * IN_DIM + f]                 = s0 / fmaxf((float)d0, 1.0f);
        M1[((size_t)N_NODES + node) * IN_DIM + f]     = s1 / fmaxf((float)d1, 1.0f);
    }
}

__global__ __launch_bounds__(256) void k_mean2(
    const float* __restrict__ h1,     // [N][64]
    const int2* __restrict__ od,
    const int* __restrict__ elist,
    float* __restrict__ M2,           // [2][CHUNK][64]
    int cb)                           // chunk base node
{
    int tid = threadIdx.x;
    int lane = tid & 63;
    int node = cb + blockIdx.x * 4 + (tid >> 6);
    if (node >= cb + CHUNK || node >= N_NODES) return;

    int2 o0 = od[node];
    int2 o1 = od[N_NODES + node];
    int d0 = o0.y, d1 = o1.y;
    int c0 = min(d0, 64), c1 = min(d1, 64);

    int e0r = (lane < c0) ? elist[o0.x + lane] : 0;
    int e1r = (lane < c1) ? elist[o1.x + lane] : 0;

    float a0 = 0, a1 = 0, a2 = 0, a3 = 0;
    float a4 = 0, a5 = 0, a6 = 0, a7 = 0;
    int dmax = max(c0, c1);
    for (int k = 0; k < dmax; k += 4) {
        int s00 = __shfl(e0r, k);
        int s01 = __shfl(e0r, k + 1);
        int s02 = __shfl(e0r, k + 2);
        int s03 = __shfl(e0r, k + 3);
        int s10 = __shfl(e1r, k);
        int s11 = __shfl(e1r, k + 1);
        int s12 = __shfl(e1r, k + 2);
        int s13 = __shfl(e1r, k + 3);
        a0 += (k     < c0) ? h1[(size_t)s00 * HID_DIM + lane] : 0.0f;
        a1 += (k + 1 < c0) ? h1[(size_t)s01 * HID_DIM + lane] : 0.0f;
        a2 += (k + 2 < c0) ? h1[(size_t)s02 * HID_DIM + lane] : 0.0f;
        a3 += (k + 3 < c0) ? h1[(size_t)s03 * HID_DIM + lane] : 0.0f;
        a4 += (k     < c1) ? h1[(size_t)s10 * HID_DIM + lane] : 0.0f;
        a5 += (k + 1 < c1) ? h1[(size_t)s11 * HID_DIM + lane] : 0.0f;
        a6 += (k + 2 < c1) ? h1[(size_t)s12 * HID_DIM + lane] : 0.0f;
        a7 += (k + 3 < c1) ? h1[(size_t)s13 * HID_DIM + lane] : 0.0f;
    }
    if (d0 > 64) {
        for (int base = 64; base < d0; base += 64) {
            int nb = min(d0 - base, 64);
            int er = (lane < nb) ? elist[o0.x + base + lane] : 0;
            for (int k = 0; k < nb; k += 4) {
                int sA = __shfl(er, k);
                int sB = __shfl(er, k + 1);
                int sC = __shfl(er, k + 2);
                int sD = __shfl(er, k + 3);
                a0 += (k     < nb) ? h1[(size_t)sA * HID_DIM + lane] : 0.0f;
                a1 += (k + 1 < nb) ? h1[(size_t)sB * HID_DIM + lane] : 0.0f;
                a2 += (k + 2 < nb) ? h1[(size_t)sC * HID_DIM + lane] : 0.0f;
                a3 += (k + 3 < nb) ? h1[(size_t)sD * HID_DIM + lane] : 0.0f;
            }
        }
    }
    if (d1 > 64) {
        for (int base = 64; base < d1; base += 64) {
            int nb = min(d1 - base, 64);
            int er = (lane < nb) ? elist[o1.x + base + lane] : 0;
            for (int k = 0; k < nb; k += 4) {
                int sA = __shfl(er, k);
                int sB = __shfl(er, k + 1);
                int sC = __shfl(er, k + 2);
                int sD = __shfl(er, k + 3);
                a4 += (k     < nb) ? h1[(size_t)sA * HID_DIM + lane] : 0.0f;
                a5 += (k + 1 < nb) ? h1[(size_t)sB * HID_DIM + lane] : 0.0f;
                a6 += (k + 2 < nb) ? h1[(size_t)sC * HID_DIM + lane] : 0.0f;
                a7 += (k + 3 < nb) ? h1[(size_t)sD * HID_DIM + lane] : 0.0f;
            }
        }
    }

    float s0 = (a0 + a1) + (a2 + a3);
    float s1 = (a4 + a5) + (a6 + a7);
    M2[((size_t)(node - cb)) * HID_DIM + lane]                 = s0 / fmaxf((float)d0, 1.0f);
    M2[((size_t)CHUNK + (node - cb)) * HID_DIM + lane]         = s1 / fmaxf((float)d1, 1.0f);
}

// ============ register-blocked matmul kernels (round-6 structure) ============
// 512 threads = 8 waves; lane = output feature j; 4 nodes register-blocked;
// 32 nodes/block. Register-lean inner loop (one matrix at a time) +
// __launch_bounds__(512,8) keeps VGPR <= 64 -> LDS-capped occupancy.
// CRITICAL: kk loop stays #pragma unroll 1 (full unroll spills -> 3.1 GB
// scratch traffic, rounds 0-2).

#define ACC4(acc, v, wa, wb, wc_, wd) \
    acc = fmaf((v).x, wa, acc);       \
    acc = fmaf((v).y, wb, acc);       \
    acc = fmaf((v).z, wc_, acc);      \
    acc = fmaf((v).w, wd, acc);

__global__ __launch_bounds__(512, 8) void k_layer1(
    const float* __restrict__ x,      // [N][32]
    const float* __restrict__ M1,     // [2][N][32] (pre-divided means)
    const float* __restrict__ root1,  // [32][64]
    const float* __restrict__ W1,     // [2][32][64]
    const float* __restrict__ b1,     // [64]
    float* __restrict__ h1)           // [N][64]
{
    __shared__ float wR[IN_DIM * HID_DIM];
    __shared__ float w0[IN_DIM * HID_DIM];
    __shared__ float w1s[IN_DIM * HID_DIM];
    int tid = threadIdx.x;
    for (int i = tid; i < IN_DIM * HID_DIM; i += 512) {
        wR[i]  = root1[i];
        w0[i]  = W1[i];
        w1s[i] = W1[IN_DIM * HID_DIM + i];
    }
    __syncthreads();

    int j  = tid & 63;
    int n0 = __builtin_amdgcn_readfirstlane(blockIdx.x * 32 + (tid >> 6) * 4);
    if (n0 >= N_NODES) return;

    const float* px = x  + (size_t)n0 * IN_DIM;
    const float* p0 = M1 + (size_t)n0 * IN_DIM;
    const float* p1 = M1 + ((size_t)N_NODES + n0) * IN_DIM;

    float accR0 = 0, accR1 = 0, accR2 = 0, accR3 = 0;
    float acc00 = 0, acc01 = 0, acc02 = 0, acc03 = 0;
    float acc10 = 0, acc11 = 0, acc12 = 0, acc13 = 0;

#pragma unroll 1
    for (int kk = 0; kk < IN_DIM / 4; ++kk) {
        int kbase = kk * 4;
        int wb_i  = kbase * 64 + j;
        {
            float wa = wR[wb_i], wb = wR[wb_i + 64], wc_ = wR[wb_i + 128], wd = wR[wb_i + 192];
            float4 v0 = *(const float4*)(px + 0 * IN_DIM + kbase);
            float4 v1 = *(const float4*)(px + 1 * IN_DIM + kbase);
            float4 v2 = *(const float4*)(px + 2 * IN_DIM + kbase);
            float4 v3 = *(const float4*)(px + 3 * IN_DIM + kbase);
            ACC4(accR0, v0, wa, wb, wc_, wd)
            ACC4(accR1, v1, wa, wb, wc_, wd)
            ACC4(accR2, v2, wa, wb, wc_, wd)
            ACC4(accR3, v3, wa, wb, wc_, wd)
        }
        {
            float wa = w0[wb_i], wb = w0[wb_i + 64], wc_ = w0[wb_i + 128], wd = w0[wb_i + 192];
            float4 v0 = *(const float4*)(p0 + 0 * IN_DIM + kbase);
            float4 v1 = *(const float4*)(p0 + 1 * IN_DIM + kbase);
            float4 v2 = *(const float4*)(p0 + 2 * IN_DIM + kbase);
            float4 v3 = *(const float4*)(p0 + 3 * IN_DIM + kbase);
            ACC4(acc00, v0, wa, wb, wc_, wd)
            ACC4(acc01, v1, wa, wb, wc_, wd)
            ACC4(acc02, v2, wa, wb, wc_, wd)
            ACC4(acc03, v3, wa, wb, wc_, wd)
        }
        {
            float wa = w1s[wb_i], wb = w1s[wb_i + 64], wc_ = w1s[wb_i + 128], wd = w1s[wb_i + 192];
            float4 v0 = *(const float4*)(p1 + 0 * IN_DIM + kbase);
            float4 v1 = *(const float4*)(p1 + 1 * IN_DIM + kbase);
            float4 v2 = *(const float4*)(p1 + 2 * IN_DIM + kbase);
            float4 v3 = *(const float4*)(p1 + 3 * IN_DIM + kbase);
            ACC4(acc10, v0, wa, wb, wc_, wd)
            ACC4(acc11, v1, wa, wb, wc_, wd)
            ACC4(acc12, v2, wa, wb, wc_, wd)
            ACC4(acc13, v3, wa, wb, wc_, wd)
        }
    }

    float bj = b1[j];
    h1[(size_t)(n0 + 0) * HID_DIM + j] = fmaxf(accR0 + bj + acc00 + acc10, 0.0f);
    h1[(size_t)(n0 + 1) * HID_DIM + j] = fmaxf(accR1 + bj + acc01 + acc11, 0.0f);
    h1[(size_t)(n0 + 2) * HID_DIM + j] = fmaxf(accR2 + bj + acc02 + acc12, 0.0f);
    h1[(size_t)(n0 + 3) * HID_DIM + j] = fmaxf(accR3 + bj + acc03 + acc13, 0.0f);
}

__global__ __launch_bounds__(512, 8) void k_layer2_cls(
    const float* __restrict__ h1,     // [N][64]
    const float* __restrict__ M2,     // [2][CHUNK][64]
    const float* __restrict__ root2,  // [64][64]
    const float* __restrict__ W2,     // [2][64][64]
    const float* __restrict__ b2,     // [64]
    const float* __restrict__ Wc,     // [64][2]
    const float* __restrict__ bc,     // [2]
    float* __restrict__ out,          // [N][2]
    int c0)
{
    __shared__ float wR[HID_DIM * HID_DIM];
    __shared__ float w0[HID_DIM * HID_DIM];
    __shared__ float w1s[HID_DIM * HID_DIM];
    __shared__ float wc[HID_DIM * 2];
    int tid = threadIdx.x;
    for (int i = tid; i < HID_DIM * HID_DIM; i += 512) {
        wR[i]  = root2[i];
        w0[i]  = W2[i];
        w1s[i] = W2[HID_DIM * HID_DIM + i];
    }
    if (tid < HID_DIM * 2) wc[tid] = Wc[tid];
    __syncthreads();

    int j  = tid & 63;
    int n0 = __builtin_amdgcn_readfirstlane(c0 + blockIdx.x * 32 + (tid >> 6) * 4);
    if (n0 >= c0 + CHUNK || n0 >= N_NODES) return;
    size_t cc = (size_t)(n0 - c0);

    const float* px = h1 + (size_t)n0 * HID_DIM;
    const float* p0 = M2 + cc * HID_DIM;
    const float* p1 = M2 + ((size_t)CHUNK + cc) * HID_DIM;

    float accR0 = 0, accR1 = 0, accR2 = 0, accR3 = 0;
    float acc00 = 0, acc01 = 0, acc02 = 0, acc03 = 0;
    float acc10 = 0, acc11 = 0, acc12 = 0, acc13 = 0;

#pragma unroll 1
    for (int kk = 0; kk < HID_DIM / 4; ++kk) {
        int kbase = kk * 4;
        int wb_i  = kbase * 64 + j;
        {
            float wa = wR[wb_i], wb = wR[wb_i + 64], wc_ = wR[wb_i + 128], wd = wR[wb_i + 192];
            float4 v0 = *(const float4*)(px + 0 * HID_DIM + kbase);
            float4 v1 = *(const float4*)(px + 1 * HID_DIM + kbase);
            float4 v2 = *(const float4*)(px + 2 * HID_DIM + kbase);
            float4 v3 = *(const float4*)(px + 3 * HID_DIM + kbase);
            ACC4(accR0, v0, wa, wb, wc_, wd)
            ACC4(accR1, v1, wa, wb, wc_, wd)
            ACC4(accR2, v2, wa, wb, wc_, wd)
            ACC4(accR3, v3, wa, wb, wc_, wd)
        }
        {
            float wa = w0[wb_i], wb = w0[wb_i + 64], wc_ = w0[wb_i + 128], wd = w0[wb_i + 192];
            float4 v0 = *(const float4*)(p0 + 0 * HID_DIM + kbase);
            float4 v1 = *(const float4*)(p0 + 1 * HID_DIM + kbase);
            float4 v2 = *(const float4*)(p0 + 2 * HID_DIM + kbase);
            float4 v3 = *(const float4*)(p0 + 3 * HID_DIM + kbase);
            ACC4(acc00, v0, wa, wb, wc_, wd)
            ACC4(acc01, v1, wa, wb, wc_, wd)
            ACC4(acc02, v2, wa, wb, wc_, wd)
            ACC4(acc03, v3, wa, wb, wc_, wd)
        }
        {
            float wa = w1s[wb_i], wb = w1s[wb_i + 64], wc_ = w1s[wb_i + 128], wd = w1s[wb_i + 192];
            float4 v0 = *(const float4*)(p1 + 0 * HID_DIM + kbase);
            float4 v1 = *(const float4*)(p1 + 1 * HID_DIM + kbase);
            float4 v2 = *(const float4*)(p1 + 2 * HID_DIM + kbase);
            float4 v3 = *(const float4*)(p1 + 3 * HID_DIM + kbase);
            ACC4(acc10, v0, wa, wb, wc_, wd)
            ACC4(acc11, v1, wa, wb, wc_, wd)
            ACC4(acc12, v2, wa, wb, wc_, wd)
            ACC4(acc13, v3, wa, wb, wc_, wd)
        }
    }

    float bj  = b2[j];
    float wcj0 = wc[2 * j], wcj1 = wc[2 * j + 1];
    float bc0 = bc[0], bc1 = bc[1];

#define L2_OUT(i, accR, acc0, acc1)                                           \
    {                                                                         \
        int n = n0 + i;                                                       \
        float h2 = fmaxf(accR + bj + acc0 + acc1, 0.0f);                      \
        float v0 = h2 * wcj0;                                                 \
        float v1 = h2 * wcj1;                                                 \
        for (int off = 32; off >= 1; off >>= 1) {                             \
            v0 += __shfl_xor(v0, off);                                        \
            v1 += __shfl_xor(v1, off);                                        \
        }                                                                     \
        if (j == 0) {                                                         \
            out[(size_t)n * 2 + 0] = v0 + bc0;                                \
            out[(size_t)n * 2 + 1] = v1 + bc1;                                \
        }                                                                     \
    }
    L2_OUT(0, accR0, acc00, acc10)
    L2_OUT(1, accR1, acc01, acc11)
    L2_OUT(2, accR2, acc02, acc12)
    L2_OUT(3, accR3, acc03, acc13)
#undef L2_OUT
}

// ============ launch ============

extern "C" void kernel_launch(void* const* d_in, const int* in_sizes, int n_in,
                              void* d_out, int out_size, void* d_ws, size_t ws_size,
                              hipStream_t stream) {
    const float* x     = (const float*)d_in[0];
    const int*   ei    = (const int*)d_in[1];
    const int*   ea    = (const int*)d_in[2];
    const float* W1    = (const float*)d_in[3];
    const float* root1 = (const float*)d_in[4];
    const float* b1    = (const float*)d_in[5];
    const float* W2    = (const float*)d_in[6];
    const float* root2 = (const float*)d_in[7];
    const float* b2    = (const float*)d_in[8];
    const float* Wc    = (const float*)d_in[9];
    const float* bc    = (const float*)d_in[10];
    float* out = (float*)d_out;

    // ws layout (bytes), peak 58.4 MB (proven budget >= 77.6 MB):
    //   deg   @ 0        : 2N int  (800000)
    //   offs  @ 800000   : 2N int  (800000)   scan intermediate
    //   od    @ 1600000  : 2N int2 (1600000)  packed (off,deg)
    //   elist @ 3200000  : E int   (4000000)
    //   h1    @ 7200000  : N*64 f32 (25600000)
    //   MB    @ 32800000 : 25.6 MB, time-shared:
    //     CSR build: cursor (2N int) + bsum (1024 int)
    //     then M1 [2][N][32] f32; then M2 [2][CHUNK][64] f32 per chunk
    char* ws = (char*)d_ws;
    int*   deg    = (int*)(ws);
    int*   offs   = (int*)(ws + 800000);
    int2*  od     = (int2*)(ws + 1600000);
    int*   elist  = (int*)(ws + 3200000);
    float* h1     = (float*)(ws + 7200000);
    char*  MB     = ws + 32800000;
    int*   cursor = (int*)(MB);
    int*   bsum   = (int*)(MB + 800000);
    float* M1     = (float*)(MB);
    float* M2     = (float*)(MB);

    const int nblk_scan = (N2 + 255) / 256;                     // 782
    const int grid_cf   = ((N_EDGES + ECHUNK - 1) / ECHUNK) * NRANGE;  // 489*8

    hipMemsetAsync(deg, 0, (size_t)N2 * 4, stream);
    k_count<<<grid_cf, 256, 0, stream>>>(ei, ea, deg);
    k_scan_local<<<nblk_scan, 256, 0, stream>>>(deg, offs, bsum);
    k_scan_blocks<<<1, 64, 0, stream>>>(bsum, nblk_scan);
    k_scan_add<<<nblk_scan, 256, 0, stream>>>(offs, bsum, deg, cursor, od);
    k_fill<<<grid_cf, 256, 0, stream>>>(ei, ea, cursor, elist);

    // layer 1: means then register-blocked matmul (32 nodes/block)
    k_mean1<<<N_NODES / 4, 256, 0, stream>>>(x, od, elist, M1);
    k_layer1<<<N_NODES / 32, 512, 0, stream>>>(x, M1, root1, W1, b1, h1);

    // layer 2 + classifier, chunked so M2 fits the MB region
    const int grid_c = (CHUNK + 31) / 32;          // 1563
    for (int c = 0; c < 2; ++c) {
        int c0 = c * CHUNK;
        k_mean2<<<CHUNK / 4, 256, 0, stream>>>(h1, od, elist, M2, c0);
        k_layer2_cls<<<grid_c, 512, 0, stream>>>(h1, M2, root2, W2, b2, Wc, bc, out, c0);
    }
}

// Round 8
// 272.704 us; speedup vs baseline: 6.7447x; 1.3469x over previous
//
#include <hip/hip_runtime.h>

#define N_NODES 100000
#define N_EDGES 1000000
#define IN_DIM 32
#define HID_DIM 64
#define N2 (2 * N_NODES)          // (rel,node) buckets
#define NRANGE 8                  // dst ranges == XCD count
#define RNODES (N_NODES / NRANGE) // 12500
#define ECHUNK 2048               // edges per block-chunk in count/fill

// ============ CSR build: XCD-local histogram -> scan -> XCD-local fill ============

__global__ __launch_bounds__(256) void k_count(
    const int* __restrict__ ei, const int* __restrict__ ea,
    int* __restrict__ deg)
{
    int range = blockIdx.x & (NRANGE - 1);
    int chunk = blockIdx.x >> 3;
    int lo = range * RNODES;
    int e0 = chunk * ECHUNK;
    int e1 = min(e0 + ECHUNK, N_EDGES);
    for (int e = e0 + threadIdx.x; e < e1; e += 256) {
        int dst = ei[N_EDGES + e];
        if ((unsigned)(dst - lo) < (unsigned)RNODES) {
            int rel = ea[2 * e + 1];
            atomicAdd(&deg[rel * N_NODES + dst], 1);
        }
    }
}

__global__ __launch_bounds__(256) void k_scan_local(
    const int* __restrict__ deg, int* __restrict__ offs, int* __restrict__ bsum)
{
    int t = threadIdx.x;
    int i = blockIdx.x * 256 + t;
    int v = (i < N2) ? deg[i] : 0;
    int lane = t & 63, w = t >> 6;
    int s = v;
#pragma unroll
    for (int off = 1; off < 64; off <<= 1) {
        int u = __shfl_up(s, off);
        if (lane >= off) s += u;
    }
    __shared__ int wsum[4];
    if (lane == 63) wsum[w] = s;
    __syncthreads();
    int add = 0;
    for (int ww = 0; ww < w; ++ww) add += wsum[ww];
    s += add;
    if (i < N2) offs[i] = s - v;
    if (t == 255) bsum[blockIdx.x] = s;
}

__global__ __launch_bounds__(64) void k_scan_blocks(int* __restrict__ bsum, int nblk)
{
    int lane = threadIdx.x;  // single wave
    int carry = 0;
    for (int base = 0; base < nblk; base += 64) {
        int i = base + lane;
        int v = (i < nblk) ? bsum[i] : 0;
        int s = v;
#pragma unroll
        for (int off = 1; off < 64; off <<= 1) {
            int u = __shfl_up(s, off);
            if (lane >= off) s += u;
        }
        if (i < nblk) bsum[i] = carry + s - v;
        carry += __shfl(s, 63);
    }
}

__global__ __launch_bounds__(256) void k_scan_add(
    const int* __restrict__ offs, const int* __restrict__ bsum,
    const int* __restrict__ deg,
    int* __restrict__ cursor, int2* __restrict__ od)
{
    int i = blockIdx.x * 256 + threadIdx.x;
    if (i >= N2) return;
    int o = offs[i] + bsum[i >> 8];
    cursor[i] = o;
    od[i] = make_int2(o, deg[i]);
}

__global__ __launch_bounds__(256) void k_fill(
    const int* __restrict__ ei, const int* __restrict__ ea,
    int* __restrict__ cursor, int* __restrict__ elist)
{
    int range = blockIdx.x & (NRANGE - 1);
    int chunk = blockIdx.x >> 3;
    int lo = range * RNODES;
    int e0 = chunk * ECHUNK;
    int e1 = min(e0 + ECHUNK, N_EDGES);
    for (int e = e0 + threadIdx.x; e < e1; e += 256) {
        int dst = ei[N_EDGES + e];
        if ((unsigned)(dst - lo) < (unsigned)RNODES) {
            int rel = ea[2 * e + 1];
            int src = ei[e];
            int pos = atomicAdd(&cursor[rel * N_NODES + dst], 1);
            elist[pos] = src;
        }
    }
}

// ============ fused layer kernels: mean -> LDS -> register-blocked matmul ============
// 512 threads = 8 waves, 32 nodes/block (4/wave). Phase A stages weights to
// LDS. Phase B: each wave gather-means its own 4 nodes (both rels interleaved,
// predicated loads) into a PER-WAVE LDS patch (no cross-wave sharing -> only
// the weight barrier is needed). Phase C: matmul; per kk-iter ALL 12 operand
// float4s are loaded up front (4 global self-rows + 8 wave-uniform LDS mean
// broadcasts) -- round-7's VGPR=20 build serialized loads (73 us, VALU 16%).
// __launch_bounds__(512,4): 128-VGPR cap gives the scheduler room for the
// 12-deep pipeline. kk loop stays "#pragma unroll 1" (full unroll spills ->
// 3.1 GB scratch, rounds 0-2).

#define ACC4(acc, v, wa, wb, wc_, wd) \
    acc = fmaf((v).x, wa, acc);       \
    acc = fmaf((v).y, wb, acc);       \
    acc = fmaf((v).z, wc_, acc);      \
    acc = fmaf((v).w, wd, acc);

__global__ __launch_bounds__(512, 4) void k_flayer1(
    const float* __restrict__ x,      // [N][32]
    const int2* __restrict__ od,      // [2N] (off,deg)
    const int* __restrict__ elist,    // [E]
    const float* __restrict__ root1,  // [32][64]
    const float* __restrict__ W1,     // [2][32][64]
    const float* __restrict__ b1,     // [64]
    float* __restrict__ h1)           // [N][64]
{
    __shared__ float wR[IN_DIM * HID_DIM];
    __shared__ float w0[IN_DIM * HID_DIM];
    __shared__ float w1s[IN_DIM * HID_DIM];
    __shared__ float mlds[8][2][4][IN_DIM];   // per-wave mean patch, 8 KB
    int tid = threadIdx.x;
    for (int i = tid; i < IN_DIM * HID_DIM; i += 512) {
        wR[i]  = root1[i];
        w0[i]  = W1[i];
        w1s[i] = W1[IN_DIM * HID_DIM + i];
    }
    // no barrier yet: mean phase doesn't read the weight arrays

    int lane = tid & 63;
    int wv   = __builtin_amdgcn_readfirstlane(tid >> 6);
    int n0   = __builtin_amdgcn_readfirstlane(blockIdx.x * 32 + wv * 4);
    int f = lane & 31, slot = lane >> 5;

    // ---- Phase B: gather-means for 4 nodes ----
    for (int i = 0; i < 4; ++i) {
        int node = n0 + i;
        int2 o0 = od[node];
        int2 o1 = od[N_NODES + node];
        int d0 = o0.y, d1 = o1.y;
        int c0 = min(d0, 64), c1 = min(d1, 64);

        int e0r = (lane < c0) ? elist[o0.x + lane] : 0;
        int e1r = (lane < c1) ? elist[o1.x + lane] : 0;

        float a0 = 0, a1 = 0, a2 = 0, a3 = 0;
        int dmax = max(c0, c1);
        for (int k = 0; k < dmax; k += 4) {
            int s00 = __shfl(e0r, k + slot);
            int s01 = __shfl(e0r, k + 2 + slot);
            int s10 = __shfl(e1r, k + slot);
            int s11 = __shfl(e1r, k + 2 + slot);
            a0 += (k + slot     < c0) ? x[(size_t)s00 * IN_DIM + f] : 0.0f;
            a1 += (k + 2 + slot < c0) ? x[(size_t)s01 * IN_DIM + f] : 0.0f;
            a2 += (k + slot     < c1) ? x[(size_t)s10 * IN_DIM + f] : 0.0f;
            a3 += (k + 2 + slot < c1) ? x[(size_t)s11 * IN_DIM + f] : 0.0f;
        }
        if (d0 > 64) {
            for (int base = 64; base < d0; base += 64) {
                int nb = min(d0 - base, 64);
                int er = (lane < nb) ? elist[o0.x + base + lane] : 0;
                for (int k = 0; k < nb; k += 2) {
                    int s = __shfl(er, k + slot);
                    a0 += (k + slot < nb) ? x[(size_t)s * IN_DIM + f] : 0.0f;
                }
            }
        }
        if (d1 > 64) {
            for (int base = 64; base < d1; base += 64) {
                int nb = min(d1 - base, 64);
                int er = (lane < nb) ? elist[o1.x + base + lane] : 0;
                for (int k = 0; k < nb; k += 2) {
                    int s = __shfl(er, k + slot);
                    a2 += (k + slot < nb) ? x[(size_t)s * IN_DIM + f] : 0.0f;
                }
            }
        }
        float s0 = a0 + a1; s0 += __shfl_xor(s0, 32);
        float s1 = a2 + a3; s1 += __shfl_xor(s1, 32);
        if (slot == 0) {
            mlds[wv][0][i][f] = s0 / fmaxf((float)d0, 1.0f);
            mlds[wv][1][i][f] = s1 / fmaxf((float)d1, 1.0f);
        }
    }
    __syncthreads();   // weights staged; own-wave mean writes ordered by lgkmcnt

    // ---- Phase C: matmul, 12 operand loads up front per kk ----
    int j = lane;
    const float* px = x + (size_t)n0 * IN_DIM;

    float accR0 = 0, accR1 = 0, accR2 = 0, accR3 = 0;
    float acc00 = 0, acc01 = 0, acc02 = 0, acc03 = 0;
    float acc10 = 0, acc11 = 0, acc12 = 0, acc13 = 0;

#pragma unroll 1
    for (int kk = 0; kk < IN_DIM / 4; ++kk) {
        int kbase = kk * 4;
        float4 xv0 = *(const float4*)(px + 0 * IN_DIM + kbase);
        float4 xv1 = *(const float4*)(px + 1 * IN_DIM + kbase);
        float4 xv2 = *(const float4*)(px + 2 * IN_DIM + kbase);
        float4 xv3 = *(const float4*)(px + 3 * IN_DIM + kbase);
        float4 m00 = *(const float4*)&mlds[wv][0][0][kbase];
        float4 m01 = *(const float4*)&mlds[wv][0][1][kbase];
        float4 m02 = *(const float4*)&mlds[wv][0][2][kbase];
        float4 m03 = *(const float4*)&mlds[wv][0][3][kbase];
        float4 m10 = *(const float4*)&mlds[wv][1][0][kbase];
        float4 m11 = *(const float4*)&mlds[wv][1][1][kbase];
        float4 m12 = *(const float4*)&mlds[wv][1][2][kbase];
        float4 m13 = *(const float4*)&mlds[wv][1][3][kbase];
        int wb_i = kbase * 64 + j;
        float wRa = wR[wb_i], wRb = wR[wb_i + 64], wRc = wR[wb_i + 128], wRd = wR[wb_i + 192];
        float w0a = w0[wb_i], w0b = w0[wb_i + 64], w0c = w0[wb_i + 128], w0d = w0[wb_i + 192];
        float w1a = w1s[wb_i], w1b = w1s[wb_i + 64], w1c = w1s[wb_i + 128], w1d = w1s[wb_i + 192];

        ACC4(accR0, xv0, wRa, wRb, wRc, wRd)
        ACC4(accR1, xv1, wRa, wRb, wRc, wRd)
        ACC4(accR2, xv2, wRa, wRb, wRc, wRd)
        ACC4(accR3, xv3, wRa, wRb, wRc, wRd)
        ACC4(acc00, m00, w0a, w0b, w0c, w0d)
        ACC4(acc01, m01, w0a, w0b, w0c, w0d)
        ACC4(acc02, m02, w0a, w0b, w0c, w0d)
        ACC4(acc03, m03, w0a, w0b, w0c, w0d)
        ACC4(acc10, m10, w1a, w1b, w1c, w1d)
        ACC4(acc11, m11, w1a, w1b, w1c, w1d)
        ACC4(acc12, m12, w1a, w1b, w1c, w1d)
        ACC4(acc13, m13, w1a, w1b, w1c, w1d)
    }

    float bj = b1[j];
    h1[(size_t)(n0 + 0) * HID_DIM + j] = fmaxf(accR0 + bj + acc00 + acc10, 0.0f);
    h1[(size_t)(n0 + 1) * HID_DIM + j] = fmaxf(accR1 + bj + acc01 + acc11, 0.0f);
    h1[(size_t)(n0 + 2) * HID_DIM + j] = fmaxf(accR2 + bj + acc02 + acc12, 0.0f);
    h1[(size_t)(n0 + 3) * HID_DIM + j] = fmaxf(accR3 + bj + acc03 + acc13, 0.0f);
}

__global__ __launch_bounds__(512, 4) void k_flayer2(
    const float* __restrict__ h1,     // [N][64]
    const int2* __restrict__ od,
    const int* __restrict__ elist,
    const float* __restrict__ root2,  // [64][64]
    const float* __restrict__ W2,     // [2][64][64]
    const float* __restrict__ b2,     // [64]
    const float* __restrict__ Wc,     // [64][2]
    const float* __restrict__ bc,     // [2]
    float* __restrict__ out)          // [N][2]
{
    __shared__ float wR[HID_DIM * HID_DIM];
    __shared__ float w0[HID_DIM * HID_DIM];
    __shared__ float w1s[HID_DIM * HID_DIM];
    __shared__ float wc[HID_DIM * 2];
    __shared__ float mlds[8][2][4][HID_DIM];   // per-wave mean patch, 16 KB
    int tid = threadIdx.x;
    for (int i = tid; i < HID_DIM * HID_DIM; i += 512) {
        wR[i]  = root2[i];
        w0[i]  = W2[i];
        w1s[i] = W2[HID_DIM * HID_DIM + i];
    }
    if (tid < HID_DIM * 2) wc[tid] = Wc[tid];

    int lane = tid & 63;
    int wv   = __builtin_amdgcn_readfirstlane(tid >> 6);
    int n0   = __builtin_amdgcn_readfirstlane(blockIdx.x * 32 + wv * 4);

    // ---- Phase B: gather-means for 4 nodes (lane = feature 0..63) ----
    for (int i = 0; i < 4; ++i) {
        int node = n0 + i;
        int2 o0 = od[node];
        int2 o1 = od[N_NODES + node];
        int d0 = o0.y, d1 = o1.y;
        int c0 = min(d0, 64), c1 = min(d1, 64);

        int e0r = (lane < c0) ? elist[o0.x + lane] : 0;
        int e1r = (lane < c1) ? elist[o1.x + lane] : 0;

        float a0 = 0, a1 = 0, a2 = 0, a3 = 0;
        float a4 = 0, a5 = 0, a6 = 0, a7 = 0;
        int dmax = max(c0, c1);
        for (int k = 0; k < dmax; k += 4) {
            int s00 = __shfl(e0r, k);
            int s01 = __shfl(e0r, k + 1);
            int s02 = __shfl(e0r, k + 2);
            int s03 = __shfl(e0r, k + 3);
            int s10 = __shfl(e1r, k);
            int s11 = __shfl(e1r, k + 1);
            int s12 = __shfl(e1r, k + 2);
            int s13 = __shfl(e1r, k + 3);
            a0 += (k     < c0) ? h1[(size_t)s00 * HID_DIM + lane] : 0.0f;
            a1 += (k + 1 < c0) ? h1[(size_t)s01 * HID_DIM + lane] : 0.0f;
            a2 += (k + 2 < c0) ? h1[(size_t)s02 * HID_DIM + lane] : 0.0f;
            a3 += (k + 3 < c0) ? h1[(size_t)s03 * HID_DIM + lane] : 0.0f;
            a4 += (k     < c1) ? h1[(size_t)s10 * HID_DIM + lane] : 0.0f;
            a5 += (k + 1 < c1) ? h1[(size_t)s11 * HID_DIM + lane] : 0.0f;
            a6 += (k + 2 < c1) ? h1[(size_t)s12 * HID_DIM + lane] : 0.0f;
            a7 += (k + 3 < c1) ? h1[(size_t)s13 * HID_DIM + lane] : 0.0f;
        }
        if (d0 > 64) {
            for (int base = 64; base < d0; base += 64) {
                int nb = min(d0 - base, 64);
                int er = (lane < nb) ? elist[o0.x + base + lane] : 0;
                for (int k = 0; k < nb; k += 4) {
                    int sA = __shfl(er, k);
                    int sB = __shfl(er, k + 1);
                    int sC = __shfl(er, k + 2);
                    int sD = __shfl(er, k + 3);
                    a0 += (k     < nb) ? h1[(size_t)sA * HID_DIM + lane] : 0.0f;
                    a1 += (k + 1 < nb) ? h1[(size_t)sB * HID_DIM + lane] : 0.0f;
                    a2 += (k + 2 < nb) ? h1[(size_t)sC * HID_DIM + lane] : 0.0f;
                    a3 += (k + 3 < nb) ? h1[(size_t)sD * HID_DIM + lane] : 0.0f;
                }
            }
        }
        if (d1 > 64) {
            for (int base = 64; base < d1; base += 64) {
                int nb = min(d1 - base, 64);
                int er = (lane < nb) ? elist[o1.x + base + lane] : 0;
                for (int k = 0; k < nb; k += 4) {
                    int sA = __shfl(er, k);
                    int sB = __shfl(er, k + 1);
                    int sC = __shfl(er, k + 2);
                    int sD = __shfl(er, k + 3);
                    a4 += (k     < nb) ? h1[(size_t)sA * HID_DIM + lane] : 0.0f;
                    a5 += (k + 1 < nb) ? h1[(size_t)sB * HID_DIM + lane] : 0.0f;
                    a6 += (k + 2 < nb) ? h1[(size_t)sC * HID_DIM + lane] : 0.0f;
                    a7 += (k + 3 < nb) ? h1[(size_t)sD * HID_DIM + lane] : 0.0f;
                }
            }
        }
        mlds[wv][0][i][lane] = ((a0 + a1) + (a2 + a3)) / fmaxf((float)d0, 1.0f);
        mlds[wv][1][i][lane] = ((a4 + a5) + (a6 + a7)) / fmaxf((float)d1, 1.0f);
    }
    __syncthreads();

    // ---- Phase C: matmul ----
    int j = lane;
    const float* px = h1 + (size_t)n0 * HID_DIM;

    float accR0 = 0, accR1 = 0, accR2 = 0, accR3 = 0;
    float acc00 = 0, acc01 = 0, acc02 = 0, acc03 = 0;
    float acc10 = 0, acc11 = 0, acc12 = 0, acc13 = 0;

#pragma unroll 1
    for (int kk = 0; kk < HID_DIM / 4; ++kk) {
        int kbase = kk * 4;
        float4 xv0 = *(const float4*)(px + 0 * HID_DIM + kbase);
        float4 xv1 = *(const float4*)(px + 1 * HID_DIM + kbase);
        float4 xv2 = *(const float4*)(px + 2 * HID_DIM + kbase);
        float4 xv3 = *(const float4*)(px + 3 * HID_DIM + kbase);
        float4 m00 = *(const float4*)&mlds[wv][0][0][kbase];
        float4 m01 = *(const float4*)&mlds[wv][0][1][kbase];
        float4 m02 = *(const float4*)&mlds[wv][0][2][kbase];
        float4 m03 = *(const float4*)&mlds[wv][0][3][kbase];
        float4 m10 = *(const float4*)&mlds[wv][1][0][kbase];
        float4 m11 = *(const float4*)&mlds[wv][1][1][kbase];
        float4 m12 = *(const float4*)&mlds[wv][1][2][kbase];
        float4 m13 = *(const float4*)&mlds[wv][1][3][kbase];
        int wb_i = kbase * 64 + j;
        float wRa = wR[wb_i], wRb = wR[wb_i + 64], wRc = wR[wb_i + 128], wRd = wR[wb_i + 192];
        float w0a = w0[wb_i], w0b = w0[wb_i + 64], w0c = w0[wb_i + 128], w0d = w0[wb_i + 192];
        float w1a = w1s[wb_i], w1b = w1s[wb_i + 64], w1c = w1s[wb_i + 128], w1d = w1s[wb_i + 192];

        ACC4(accR0, xv0, wRa, wRb, wRc, wRd)
        ACC4(accR1, xv1, wRa, wRb, wRc, wRd)
        ACC4(accR2, xv2, wRa, wRb, wRc, wRd)
        ACC4(accR3, xv3, wRa, wRb, wRc, wRd)
        ACC4(acc00, m00, w0a, w0b, w0c, w0d)
        ACC4(acc01, m01, w0a, w0b, w0c, w0d)
        ACC4(acc02, m02, w0a, w0b, w0c, w0d)
        ACC4(acc03, m03, w0a, w0b, w0c, w0d)
        ACC4(acc10, m10, w1a, w1b, w1c, w1d)
        ACC4(acc11, m11, w1a, w1b, w1c, w1d)
        ACC4(acc12, m12, w1a, w1b, w1c, w1d)
        ACC4(acc13, m13, w1a, w1b, w1c, w1d)
    }

    float bj  = b2[j];
    float wcj0 = wc[2 * j], wcj1 = wc[2 * j + 1];
    float bc0 = bc[0], bc1 = bc[1];

#define L2_OUT(i, accR, acc0, acc1)                                           \
    {                                                                         \
        int n = n0 + i;                                                       \
        float h2 = fmaxf(accR + bj + acc0 + acc1, 0.0f);                      \
        float v0 = h2 * wcj0;                                                 \
        float v1 = h2 * wcj1;                                                 \
        for (int off = 32; off >= 1; off >>= 1) {                             \
            v0 += __shfl_xor(v0, off);                                        \
            v1 += __shfl_xor(v1, off);                                        \
        }                                                                     \
        if (j == 0) {                                                         \
            out[(size_t)n * 2 + 0] = v0 + bc0;                                \
            out[(size_t)n * 2 + 1] = v1 + bc1;                                \
        }                                                                     \
    }
    L2_OUT(0, accR0, acc00, acc10)
    L2_OUT(1, accR1, acc01, acc11)
    L2_OUT(2, accR2, acc02, acc12)
    L2_OUT(3, accR3, acc03, acc13)
#undef L2_OUT
}

// ============ launch ============

extern "C" void kernel_launch(void* const* d_in, const int* in_sizes, int n_in,
                              void* d_out, int out_size, void* d_ws, size_t ws_size,
                              hipStream_t stream) {
    const float* x     = (const float*)d_in[0];
    const int*   ei    = (const int*)d_in[1];
    const int*   ea    = (const int*)d_in[2];
    const float* W1    = (const float*)d_in[3];
    const float* root1 = (const float*)d_in[4];
    const float* b1    = (const float*)d_in[5];
    const float* W2    = (const float*)d_in[6];
    const float* root2 = (const float*)d_in[7];
    const float* b2    = (const float*)d_in[8];
    const float* Wc    = (const float*)d_in[9];
    const float* bc    = (const float*)d_in[10];
    float* out = (float*)d_out;

    // ws layout (bytes), peak ~33.6 MB:
    //   deg    @ 0        : 2N int  (800000)
    //   offs   @ 800000   : 2N int  (800000)
    //   od     @ 1600000  : 2N int2 (1600000)
    //   elist  @ 3200000  : E int   (4000000)
    //   h1     @ 7200000  : N*64 f32 (25600000)
    //   cursor @ 32800000 : 2N int  (800000)
    //   bsum   @ 33600000 : 1024 int
    char* ws = (char*)d_ws;
    int*   deg    = (int*)(ws);
    int*   offs   = (int*)(ws + 800000);
    int2*  od     = (int2*)(ws + 1600000);
    int*   elist  = (int*)(ws + 3200000);
    float* h1     = (float*)(ws + 7200000);
    int*   cursor = (int*)(ws + 32800000);
    int*   bsum   = (int*)(ws + 33600000);

    const int nblk_scan = (N2 + 255) / 256;                            // 782
    const int grid_cf   = ((N_EDGES + ECHUNK - 1) / ECHUNK) * NRANGE;  // 489*8

    hipMemsetAsync(deg, 0, (size_t)N2 * 4, stream);
    k_count<<<grid_cf, 256, 0, stream>>>(ei, ea, deg);
    k_scan_local<<<nblk_scan, 256, 0, stream>>>(deg, offs, bsum);
    k_scan_blocks<<<1, 64, 0, stream>>>(bsum, nblk_scan);
    k_scan_add<<<nblk_scan, 256, 0, stream>>>(offs, bsum, deg, cursor, od);
    k_fill<<<grid_cf, 256, 0, stream>>>(ei, ea, cursor, elist);

    k_flayer1<<<N_NODES / 32, 512, 0, stream>>>(x, od, elist, root1, W1, b1, h1);
    k_flayer2<<<N_NODES / 32, 512, 0, stream>>>(h1, od, elist, root2, W2, b2, Wc, bc, out);
}

// Round 9
// 264.010 us; speedup vs baseline: 6.9668x; 1.0329x over previous
//
#include <hip/hip_runtime.h>

#define N_NODES 100000
#define N_EDGES 1000000
#define IN_DIM 32
#define HID_DIM 64
#define N2 (2 * N_NODES)          // (rel,node) buckets
#define NRANGE 8                  // dst ranges == XCD count
#define RNODES (N_NODES / NRANGE) // 12500
#define ECHUNK 2048               // edges per block-chunk in count/fill

// ============ CSR build: XCD-local histogram -> scan -> XCD-local fill ============

__global__ __launch_bounds__(256) void k_count(
    const int* __restrict__ ei, const int* __restrict__ ea,
    int* __restrict__ deg)
{
    int range = blockIdx.x & (NRANGE - 1);
    int chunk = blockIdx.x >> 3;
    int lo = range * RNODES;
    int e0 = chunk * ECHUNK;
    int e1 = min(e0 + ECHUNK, N_EDGES);
    for (int e = e0 + threadIdx.x; e < e1; e += 256) {
        int dst = ei[N_EDGES + e];
        if ((unsigned)(dst - lo) < (unsigned)RNODES) {
            int rel = ea[2 * e + 1];
            atomicAdd(&deg[rel * N_NODES + dst], 1);
        }
    }
}

__global__ __launch_bounds__(256) void k_scan_local(
    const int* __restrict__ deg, int* __restrict__ offs, int* __restrict__ bsum)
{
    int t = threadIdx.x;
    int i = blockIdx.x * 256 + t;
    int v = (i < N2) ? deg[i] : 0;
    int lane = t & 63, w = t >> 6;
    int s = v;
#pragma unroll
    for (int off = 1; off < 64; off <<= 1) {
        int u = __shfl_up(s, off);
        if (lane >= off) s += u;
    }
    __shared__ int wsum[4];
    if (lane == 63) wsum[w] = s;
    __syncthreads();
    int add = 0;
    for (int ww = 0; ww < w; ++ww) add += wsum[ww];
    s += add;
    if (i < N2) offs[i] = s - v;
    if (t == 255) bsum[blockIdx.x] = s;
}

__global__ __launch_bounds__(64) void k_scan_blocks(int* __restrict__ bsum, int nblk)
{
    int lane = threadIdx.x;  // single wave
    int carry = 0;
    for (int base = 0; base < nblk; base += 64) {
        int i = base + lane;
        int v = (i < nblk) ? bsum[i] : 0;
        int s = v;
#pragma unroll
        for (int off = 1; off < 64; off <<= 1) {
            int u = __shfl_up(s, off);
            if (lane >= off) s += u;
        }
        if (i < nblk) bsum[i] = carry + s - v;
        carry += __shfl(s, 63);
    }
}

__global__ __launch_bounds__(256) void k_scan_add(
    const int* __restrict__ offs, const int* __restrict__ bsum,
    const int* __restrict__ deg,
    int* __restrict__ cursor, int2* __restrict__ od)
{
    int i = blockIdx.x * 256 + threadIdx.x;
    if (i >= N2) return;
    int o = offs[i] + bsum[i >> 8];
    cursor[i] = o;
    od[i] = make_int2(o, deg[i]);
}

__global__ __launch_bounds__(256) void k_fill(
    const int* __restrict__ ei, const int* __restrict__ ea,
    int* __restrict__ cursor, int* __restrict__ elist)
{
    int range = blockIdx.x & (NRANGE - 1);
    int chunk = blockIdx.x >> 3;
    int lo = range * RNODES;
    int e0 = chunk * ECHUNK;
    int e1 = min(e0 + ECHUNK, N_EDGES);
    for (int e = e0 + threadIdx.x; e < e1; e += 256) {
        int dst = ei[N_EDGES + e];
        if ((unsigned)(dst - lo) < (unsigned)RNODES) {
            int rel = ea[2 * e + 1];
            int src = ei[e];
            int pos = atomicAdd(&cursor[rel * N_NODES + dst], 1);
            elist[pos] = src;
        }
    }
}

// ============ fused layer kernels ============
// float4-QUAD GATHER (round-9): lane loads 16 B of a row, so one wave-load
// covers 4 rows (layer2, 256 B rows) / 8 rows (layer1, 128 B rows). VMEM
// instrs, bpermutes and addr VALU are /4 (/8) vs the 4 B/lane gather that
// made round-8 VALU-issue-bound (52% VALUBusy). Both rels issued per iter
// with float-mask accumulate (er[idx]=0 for idx>=nb -> safe row 0, masked).
// Cross-row-group reduce: shfl_xor steps on the float4, then low lanes write
// the mean float4 to the per-wave LDS patch (matmul layout unchanged).
// kk loop stays "#pragma unroll 1" (full unroll spills, rounds 0-2).

#define ACC4(acc, v, wa, wb, wc_, wd) \
    acc = fmaf((v).x, wa, acc);       \
    acc = fmaf((v).y, wb, acc);       \
    acc = fmaf((v).z, wc_, acc);      \
    acc = fmaf((v).w, wd, acc);

#define MACC4(A, v, m)                \
    A.x = fmaf((v).x, m, A.x);        \
    A.y = fmaf((v).y, m, A.y);        \
    A.z = fmaf((v).z, m, A.z);        \
    A.w = fmaf((v).w, m, A.w);

__global__ __launch_bounds__(512, 4) void k_flayer1(
    const float* __restrict__ x,      // [N][32]
    const int2* __restrict__ od,      // [2N] (off,deg)
    const int* __restrict__ elist,    // [E]
    const float* __restrict__ root1,  // [32][64]
    const float* __restrict__ W1,     // [2][32][64]
    const float* __restrict__ b1,     // [64]
    float* __restrict__ h1)           // [N][64]
{
    __shared__ float wR[IN_DIM * HID_DIM];
    __shared__ float w0[IN_DIM * HID_DIM];
    __shared__ float w1s[IN_DIM * HID_DIM];
    __shared__ float mlds[8][2][4][IN_DIM];   // per-wave mean patch, 8 KB
    int tid = threadIdx.x;
    for (int i = tid; i < IN_DIM * HID_DIM; i += 512) {
        wR[i]  = root1[i];
        w0[i]  = W1[i];
        w1s[i] = W1[IN_DIM * HID_DIM + i];
    }

    int lane = tid & 63;
    int wv   = __builtin_amdgcn_readfirstlane(tid >> 6);
    int n0   = __builtin_amdgcn_readfirstlane(blockIdx.x * 32 + wv * 4);
    int rg = lane >> 3;       // row-group 0..7 (8 rows per wave-load)
    int fq = lane & 7;        // feature quad: features 4*fq .. 4*fq+3

    // ---- Phase B: quad-gather means for 4 nodes ----
#pragma unroll 1
    for (int i = 0; i < 4; ++i) {
        int node = n0 + i;
        int2 o0 = od[node];
        int2 o1 = od[N_NODES + node];
        int d0 = o0.y, d1 = o1.y;
        int c0 = min(d0, 64), c1 = min(d1, 64);
        int er0 = (lane < c0) ? elist[o0.x + lane] : 0;
        int er1 = (lane < c1) ? elist[o1.x + lane] : 0;

        float4 A0 = make_float4(0.f, 0.f, 0.f, 0.f);
        float4 A1 = make_float4(0.f, 0.f, 0.f, 0.f);
        int dmax = max(c0, c1);
        for (int k = 0; k < dmax; k += 8) {
            int s0 = __shfl(er0, k + rg);
            int s1 = __shfl(er1, k + rg);
            float4 v0 = *(const float4*)(x + (size_t)s0 * IN_DIM + fq * 4);
            float4 v1 = *(const float4*)(x + (size_t)s1 * IN_DIM + fq * 4);
            float m0 = (k + rg < c0) ? 1.0f : 0.0f;
            float m1 = (k + rg < c1) ? 1.0f : 0.0f;
            MACC4(A0, v0, m0)
            MACC4(A1, v1, m1)
        }
        if (d0 > 64) {
            for (int base = 64; base < d0; base += 64) {
                int nb = min(d0 - base, 64);
                int er = (lane < nb) ? elist[o0.x + base + lane] : 0;
                for (int k = 0; k < nb; k += 8) {
                    int s = __shfl(er, k + rg);
                    float4 v = *(const float4*)(x + (size_t)s * IN_DIM + fq * 4);
                    float m = (k + rg < nb) ? 1.0f : 0.0f;
                    MACC4(A0, v, m)
                }
            }
        }
        if (d1 > 64) {
            for (int base = 64; base < d1; base += 64) {
                int nb = min(d1 - base, 64);
                int er = (lane < nb) ? elist[o1.x + base + lane] : 0;
                for (int k = 0; k < nb; k += 8) {
                    int s = __shfl(er, k + rg);
                    float4 v = *(const float4*)(x + (size_t)s * IN_DIM + fq * 4);
                    float m = (k + rg < nb) ? 1.0f : 0.0f;
                    MACC4(A1, v, m)
                }
            }
        }
        // reduce across 8 row-groups: xor 8,16,32
#pragma unroll
        for (int off = 8; off <= 32; off <<= 1) {
            A0.x += __shfl_xor(A0.x, off); A0.y += __shfl_xor(A0.y, off);
            A0.z += __shfl_xor(A0.z, off); A0.w += __shfl_xor(A0.w, off);
            A1.x += __shfl_xor(A1.x, off); A1.y += __shfl_xor(A1.y, off);
            A1.z += __shfl_xor(A1.z, off); A1.w += __shfl_xor(A1.w, off);
        }
        float i0 = 1.0f / fmaxf((float)d0, 1.0f);
        float i1 = 1.0f / fmaxf((float)d1, 1.0f);
        if (lane < 8) {
            *(float4*)&mlds[wv][0][i][lane * 4] =
                make_float4(A0.x * i0, A0.y * i0, A0.z * i0, A0.w * i0);
            *(float4*)&mlds[wv][1][i][lane * 4] =
                make_float4(A1.x * i1, A1.y * i1, A1.z * i1, A1.w * i1);
        }
    }
    __syncthreads();

    // ---- Phase C: matmul, 12 operand loads up front per kk ----
    int j = lane;
    const float* px = x + (size_t)n0 * IN_DIM;

    float accR0 = 0, accR1 = 0, accR2 = 0, accR3 = 0;
    float acc00 = 0, acc01 = 0, acc02 = 0, acc03 = 0;
    float acc10 = 0, acc11 = 0, acc12 = 0, acc13 = 0;

#pragma unroll 1
    for (int kk = 0; kk < IN_DIM / 4; ++kk) {
        int kbase = kk * 4;
        float4 xv0 = *(const float4*)(px + 0 * IN_DIM + kbase);
        float4 xv1 = *(const float4*)(px + 1 * IN_DIM + kbase);
        float4 xv2 = *(const float4*)(px + 2 * IN_DIM + kbase);
        float4 xv3 = *(const float4*)(px + 3 * IN_DIM + kbase);
        float4 m00 = *(const float4*)&mlds[wv][0][0][kbase];
        float4 m01 = *(const float4*)&mlds[wv][0][1][kbase];
        float4 m02 = *(const float4*)&mlds[wv][0][2][kbase];
        float4 m03 = *(const float4*)&mlds[wv][0][3][kbase];
        float4 m10 = *(const float4*)&mlds[wv][1][0][kbase];
        float4 m11 = *(const float4*)&mlds[wv][1][1][kbase];
        float4 m12 = *(const float4*)&mlds[wv][1][2][kbase];
        float4 m13 = *(const float4*)&mlds[wv][1][3][kbase];
        int wb_i = kbase * 64 + j;
        float wRa = wR[wb_i], wRb = wR[wb_i + 64], wRc = wR[wb_i + 128], wRd = wR[wb_i + 192];
        float w0a = w0[wb_i], w0b = w0[wb_i + 64], w0c = w0[wb_i + 128], w0d = w0[wb_i + 192];
        float w1a = w1s[wb_i], w1b = w1s[wb_i + 64], w1c = w1s[wb_i + 128], w1d = w1s[wb_i + 192];

        ACC4(accR0, xv0, wRa, wRb, wRc, wRd)
        ACC4(accR1, xv1, wRa, wRb, wRc, wRd)
        ACC4(accR2, xv2, wRa, wRb, wRc, wRd)
        ACC4(accR3, xv3, wRa, wRb, wRc, wRd)
        ACC4(acc00, m00, w0a, w0b, w0c, w0d)
        ACC4(acc01, m01, w0a, w0b, w0c, w0d)
        ACC4(acc02, m02, w0a, w0b, w0c, w0d)
        ACC4(acc03, m03, w0a, w0b, w0c, w0d)
        ACC4(acc10, m10, w1a, w1b, w1c, w1d)
        ACC4(acc11, m11, w1a, w1b, w1c, w1d)
        ACC4(acc12, m12, w1a, w1b, w1c, w1d)
        ACC4(acc13, m13, w1a, w1b, w1c, w1d)
    }

    float bj = b1[j];
    h1[(size_t)(n0 + 0) * HID_DIM + j] = fmaxf(accR0 + bj + acc00 + acc10, 0.0f);
    h1[(size_t)(n0 + 1) * HID_DIM + j] = fmaxf(accR1 + bj + acc01 + acc11, 0.0f);
    h1[(size_t)(n0 + 2) * HID_DIM + j] = fmaxf(accR2 + bj + acc02 + acc12, 0.0f);
    h1[(size_t)(n0 + 3) * HID_DIM + j] = fmaxf(accR3 + bj + acc03 + acc13, 0.0f);
}

__global__ __launch_bounds__(512, 4) void k_flayer2(
    const float* __restrict__ h1,     // [N][64]
    const int2* __restrict__ od,
    const int* __restrict__ elist,
    const float* __restrict__ root2,  // [64][64] -- read from GLOBAL (L1-resident)
    const float* __restrict__ W2,     // [2][64][64]
    const float* __restrict__ b2,     // [64]
    const float* __restrict__ Wc,     // [64][2]
    const float* __restrict__ bc,     // [2]
    float* __restrict__ out)          // [N][2]
{
    // root2 NOT staged: 48.5 KB LDS -> 3 blocks/CU (round-8's 64.5 KB -> 2,
    // occupancy 38.7% was the latency-hiding limiter). root2 (16 KB) L1-hits.
    __shared__ float w0[HID_DIM * HID_DIM];
    __shared__ float w1s[HID_DIM * HID_DIM];
    __shared__ float wc[HID_DIM * 2];
    __shared__ float mlds[8][2][4][HID_DIM];   // per-wave mean patch, 16 KB
    int tid = threadIdx.x;
    for (int i = tid; i < HID_DIM * HID_DIM; i += 512) {
        w0[i]  = W2[i];
        w1s[i] = W2[HID_DIM * HID_DIM + i];
    }
    if (tid < HID_DIM * 2) wc[tid] = Wc[tid];

    int lane = tid & 63;
    int wv   = __builtin_amdgcn_readfirstlane(tid >> 6);
    int n0   = __builtin_amdgcn_readfirstlane(blockIdx.x * 32 + wv * 4);
    int rg = lane >> 4;       // row-group 0..3 (4 rows per wave-load)
    int fq = lane & 15;       // feature quad: features 4*fq .. 4*fq+3

    // ---- Phase B: quad-gather means for 4 nodes ----
#pragma unroll 1
    for (int i = 0; i < 4; ++i) {
        int node = n0 + i;
        int2 o0 = od[node];
        int2 o1 = od[N_NODES + node];
        int d0 = o0.y, d1 = o1.y;
        int c0 = min(d0, 64), c1 = min(d1, 64);
        int er0 = (lane < c0) ? elist[o0.x + lane] : 0;
        int er1 = (lane < c1) ? elist[o1.x + lane] : 0;

        float4 A0 = make_float4(0.f, 0.f, 0.f, 0.f);
        float4 A1 = make_float4(0.f, 0.f, 0.f, 0.f);
        int dmax = max(c0, c1);
        for (int k = 0; k < dmax; k += 4) {
            int s0 = __shfl(er0, k + rg);
            int s1 = __shfl(er1, k + rg);
            float4 v0 = *(const float4*)(h1 + (size_t)s0 * HID_DIM + fq * 4);
            float4 v1 = *(const float4*)(h1 + (size_t)s1 * HID_DIM + fq * 4);
            float m0 = (k + rg < c0) ? 1.0f : 0.0f;
            float m1 = (k + rg < c1) ? 1.0f : 0.0f;
            MACC4(A0, v0, m0)
            MACC4(A1, v1, m1)
        }
        if (d0 > 64) {
            for (int base = 64; base < d0; base += 64) {
                int nb = min(d0 - base, 64);
                int er = (lane < nb) ? elist[o0.x + base + lane] : 0;
                for (int k = 0; k < nb; k += 4) {
                    int s = __shfl(er, k + rg);
                    float4 v = *(const float4*)(h1 + (size_t)s * HID_DIM + fq * 4);
                    float m = (k + rg < nb) ? 1.0f : 0.0f;
                    MACC4(A0, v, m)
                }
            }
        }
        if (d1 > 64) {
            for (int base = 64; base < d1; base += 64) {
                int nb = min(d1 - base, 64);
                int er = (lane < nb) ? elist[o1.x + base + lane] : 0;
                for (int k = 0; k < nb; k += 4) {
                    int s = __shfl(er, k + rg);
                    float4 v = *(const float4*)(h1 + (size_t)s * HID_DIM + fq * 4);
                    float m = (k + rg < nb) ? 1.0f : 0.0f;
                    MACC4(A1, v, m)
                }
            }
        }
        // reduce across 4 row-groups: xor 16,32
#pragma unroll
        for (int off = 16; off <= 32; off <<= 1) {
            A0.x += __shfl_xor(A0.x, off); A0.y += __shfl_xor(A0.y, off);
            A0.z += __shfl_xor(A0.z, off); A0.w += __shfl_xor(A0.w, off);
            A1.x += __shfl_xor(A1.x, off); A1.y += __shfl_xor(A1.y, off);
            A1.z += __shfl_xor(A1.z, off); A1.w += __shfl_xor(A1.w, off);
        }
        float i0 = 1.0f / fmaxf((float)d0, 1.0f);
        float i1 = 1.0f / fmaxf((float)d1, 1.0f);
        if (lane < 16) {
            *(float4*)&mlds[wv][0][i][lane * 4] =
                make_float4(A0.x * i0, A0.y * i0, A0.z * i0, A0.w * i0);
            *(float4*)&mlds[wv][1][i][lane * 4] =
                make_float4(A1.x * i1, A1.y * i1, A1.z * i1, A1.w * i1);
        }
    }
    __syncthreads();

    // ---- Phase C: matmul (root2 weights from global / L1) ----
    int j = lane;
    const float* px = h1 + (size_t)n0 * HID_DIM;

    float accR0 = 0, accR1 = 0, accR2 = 0, accR3 = 0;
    float acc00 = 0, acc01 = 0, acc02 = 0, acc03 = 0;
    float acc10 = 0, acc11 = 0, acc12 = 0, acc13 = 0;

#pragma unroll 1
    for (int kk = 0; kk < HID_DIM / 4; ++kk) {
        int kbase = kk * 4;
        float4 xv0 = *(const float4*)(px + 0 * HID_DIM + kbase);
        float4 xv1 = *(const float4*)(px + 1 * HID_DIM + kbase);
        float4 xv2 = *(const float4*)(px + 2 * HID_DIM + kbase);
        float4 xv3 = *(const float4*)(px + 3 * HID_DIM + kbase);
        float4 m00 = *(const float4*)&mlds[wv][0][0][kbase];
        float4 m01 = *(const float4*)&mlds[wv][0][1][kbase];
        float4 m02 = *(const float4*)&mlds[wv][0][2][kbase];
        float4 m03 = *(const float4*)&mlds[wv][0][3][kbase];
        float4 m10 = *(const float4*)&mlds[wv][1][0][kbase];
        float4 m11 = *(const float4*)&mlds[wv][1][1][kbase];
        float4 m12 = *(const float4*)&mlds[wv][1][2][kbase];
        float4 m13 = *(const float4*)&mlds[wv][1][3][kbase];
        int wb_i = kbase * 64 + j;
        float wRa = root2[wb_i], wRb = root2[wb_i + 64];
        float wRc = root2[wb_i + 128], wRd = root2[wb_i + 192];
        float w0a = w0[wb_i], w0b = w0[wb_i + 64], w0c = w0[wb_i + 128], w0d = w0[wb_i + 192];
        float w1a = w1s[wb_i], w1b = w1s[wb_i + 64], w1c = w1s[wb_i + 128], w1d = w1s[wb_i + 192];

        ACC4(accR0, xv0, wRa, wRb, wRc, wRd)
        ACC4(accR1, xv1, wRa, wRb, wRc, wRd)
        ACC4(accR2, xv2, wRa, wRb, wRc, wRd)
        ACC4(accR3, xv3, wRa, wRb, wRc, wRd)
        ACC4(acc00, m00, w0a, w0b, w0c, w0d)
        ACC4(acc01, m01, w0a, w0b, w0c, w0d)
        ACC4(acc02, m02, w0a, w0b, w0c, w0d)
        ACC4(acc03, m03, w0a, w0b, w0c, w0d)
        ACC4(acc10, m10, w1a, w1b, w1c, w1d)
        ACC4(acc11, m11, w1a, w1b, w1c, w1d)
        ACC4(acc12, m12, w1a, w1b, w1c, w1d)
        ACC4(acc13, m13, w1a, w1b, w1c, w1d)
    }

    float bj  = b2[j];
    float wcj0 = wc[2 * j], wcj1 = wc[2 * j + 1];
    float bc0 = bc[0], bc1 = bc[1];

#define L2_OUT(i, accR, acc0, acc1)                                           \
    {                                                                         \
        int n = n0 + i;                                                       \
        float h2 = fmaxf(accR + bj + acc0 + acc1, 0.0f);                      \
        float v0 = h2 * wcj0;                                                 \
        float v1 = h2 * wcj1;                                                 \
        for (int off = 32; off >= 1; off >>= 1) {                             \
            v0 += __shfl_xor(v0, off);                                        \
            v1 += __shfl_xor(v1, off);                                        \
        }                                                                     \
        if (j == 0) {                                                         \
            out[(size_t)n * 2 + 0] = v0 + bc0;                                \
            out[(size_t)n * 2 + 1] = v1 + bc1;                                \
        }                                                                     \
    }
    L2_OUT(0, accR0, acc00, acc10)
    L2_OUT(1, accR1, acc01, acc11)
    L2_OUT(2, accR2, acc02, acc12)
    L2_OUT(3, accR3, acc03, acc13)
#undef L2_OUT
}

// ============ launch ============

extern "C" void kernel_launch(void* const* d_in, const int* in_sizes, int n_in,
                              void* d_out, int out_size, void* d_ws, size_t ws_size,
                              hipStream_t stream) {
    const float* x     = (const float*)d_in[0];
    const int*   ei    = (const int*)d_in[1];
    const int*   ea    = (const int*)d_in[2];
    const float* W1    = (const float*)d_in[3];
    const float* root1 = (const float*)d_in[4];
    const float* b1    = (const float*)d_in[5];
    const float* W2    = (const float*)d_in[6];
    const float* root2 = (const float*)d_in[7];
    const float* b2    = (const float*)d_in[8];
    const float* Wc    = (const float*)d_in[9];
    const float* bc    = (const float*)d_in[10];
    float* out = (float*)d_out;

    // ws layout (bytes), peak ~33.6 MB:
    //   deg    @ 0        : 2N int  (800000)
    //   offs   @ 800000   : 2N int  (800000)
    //   od     @ 1600000  : 2N int2 (1600000)
    //   elist  @ 3200000  : E int   (4000000)
    //   h1     @ 7200000  : N*64 f32 (25600000)
    //   cursor @ 32800000 : 2N int  (800000)
    //   bsum   @ 33600000 : 1024 int
    char* ws = (char*)d_ws;
    int*   deg    = (int*)(ws);
    int*   offs   = (int*)(ws + 800000);
    int2*  od     = (int2*)(ws + 1600000);
    int*   elist  = (int*)(ws + 3200000);
    float* h1     = (float*)(ws + 7200000);
    int*   cursor = (int*)(ws + 32800000);
    int*   bsum   = (int*)(ws + 33600000);

    const int nblk_scan = (N2 + 255) / 256;                            // 782
    const int grid_cf   = ((N_EDGES + ECHUNK - 1) / ECHUNK) * NRANGE;  // 489*8

    hipMemsetAsync(deg, 0, (size_t)N2 * 4, stream);
    k_count<<<grid_cf, 256, 0, stream>>>(ei, ea, deg);
    k_scan_local<<<nblk_scan, 256, 0, stream>>>(deg, offs, bsum);
    k_scan_blocks<<<1, 64, 0, stream>>>(bsum, nblk_scan);
    k_scan_add<<<nblk_scan, 256, 0, stream>>>(offs, bsum, deg, cursor, od);
    k_fill<<<grid_cf, 256, 0, stream>>>(ei, ea, cursor, elist);

    k_flayer1<<<N_NODES / 32, 512, 0, stream>>>(x, od, elist, root1, W1, b1, h1);
    k_flayer2<<<N_NODES / 32, 512, 0, stream>>>(h1, od, elist, root2, W2, b2, Wc, bc, out);
}

// Round 10
// 258.992 us; speedup vs baseline: 7.1017x; 1.0194x over previous
//
#include <hip/hip_runtime.h>

#define N_NODES 100000
#define N_EDGES 1000000
#define IN_DIM 32
#define HID_DIM 64
#define N2 (2 * N_NODES)          // (rel,node) buckets
#define NRANGE 8                  // dst ranges == XCD count
#define RNODES (N_NODES / NRANGE) // 12500
#define ECHUNK 2048               // edges per block-chunk in count/fill

// ============ CSR build: XCD-local histogram -> scan -> XCD-local fill ============

__global__ __launch_bounds__(256) void k_count(
    const int* __restrict__ ei, const int* __restrict__ ea,
    int* __restrict__ deg)
{
    int range = blockIdx.x & (NRANGE - 1);
    int chunk = blockIdx.x >> 3;
    int lo = range * RNODES;
    int e0 = chunk * ECHUNK;
    int e1 = min(e0 + ECHUNK, N_EDGES);
    for (int e = e0 + threadIdx.x; e < e1; e += 256) {
        int dst = ei[N_EDGES + e];
        if ((unsigned)(dst - lo) < (unsigned)RNODES) {
            int rel = ea[2 * e + 1];
            atomicAdd(&deg[rel * N_NODES + dst], 1);
        }
    }
}

__global__ __launch_bounds__(256) void k_scan_local(
    const int* __restrict__ deg, int* __restrict__ offs, int* __restrict__ bsum)
{
    int t = threadIdx.x;
    int i = blockIdx.x * 256 + t;
    int v = (i < N2) ? deg[i] : 0;
    int lane = t & 63, w = t >> 6;
    int s = v;
#pragma unroll
    for (int off = 1; off < 64; off <<= 1) {
        int u = __shfl_up(s, off);
        if (lane >= off) s += u;
    }
    __shared__ int wsum[4];
    if (lane == 63) wsum[w] = s;
    __syncthreads();
    int add = 0;
    for (int ww = 0; ww < w; ++ww) add += wsum[ww];
    s += add;
    if (i < N2) offs[i] = s - v;
    if (t == 255) bsum[blockIdx.x] = s;
}

__global__ __launch_bounds__(64) void k_scan_blocks(int* __restrict__ bsum, int nblk)
{
    int lane = threadIdx.x;  // single wave
    int carry = 0;
    for (int base = 0; base < nblk; base += 64) {
        int i = base + lane;
        int v = (i < nblk) ? bsum[i] : 0;
        int s = v;
#pragma unroll
        for (int off = 1; off < 64; off <<= 1) {
            int u = __shfl_up(s, off);
            if (lane >= off) s += u;
        }
        if (i < nblk) bsum[i] = carry + s - v;
        carry += __shfl(s, 63);
    }
}

__global__ __launch_bounds__(256) void k_scan_add(
    const int* __restrict__ offs, const int* __restrict__ bsum,
    const int* __restrict__ deg,
    int* __restrict__ cursor, int2* __restrict__ od)
{
    int i = blockIdx.x * 256 + threadIdx.x;
    if (i >= N2) return;
    int o = offs[i] + bsum[i >> 8];
    cursor[i] = o;
    od[i] = make_int2(o, deg[i]);
}

__global__ __launch_bounds__(256) void k_fill(
    const int* __restrict__ ei, const int* __restrict__ ea,
    int* __restrict__ cursor, int* __restrict__ elist)
{
    int range = blockIdx.x & (NRANGE - 1);
    int chunk = blockIdx.x >> 3;
    int lo = range * RNODES;
    int e0 = chunk * ECHUNK;
    int e1 = min(e0 + ECHUNK, N_EDGES);
    for (int e = e0 + threadIdx.x; e < e1; e += 256) {
        int dst = ei[N_EDGES + e];
        if ((unsigned)(dst - lo) < (unsigned)RNODES) {
            int rel = ea[2 * e + 1];
            int src = ei[e];
            int pos = atomicAdd(&cursor[rel * N_NODES + dst], 1);
            elist[pos] = src;
        }
    }
}

// ============ fused layer kernels (round-10) ============
// SUBGROUP-PER-NODE gather + REGISTER means + v_readlane broadcast.
// Round-9 was LDS-pipe-bound in the matmul (8 b128 mean reads + 8 b32 weight
// reads = ~142 LDS cyc/iter vs ~110 VALU; 97.6 waves/CU x 2272 cyc = 92 us
// ~= measured 105). Now: wave = subgroups of row-size lanes, one node(-rel)
// per subgroup -> each wave-load fetches one edge row per subgroup, NO
// cross-subgroup reduce, and the accumulator A directly holds the mean quad
// for feature-quad (lane%G) of its node -> matmul reads means with
// v_readlane (VALU pipe) instead of LDS. mlds buffer + writes + barrier-dep
// eliminated. kk loop stays "#pragma unroll 1" (full unroll spills, r0-2).

#define ACC4(acc, v, wa, wb, wc_, wd) \
    acc = fmaf((v).x, wa, acc);       \
    acc = fmaf((v).y, wb, acc);       \
    acc = fmaf((v).z, wc_, acc);      \
    acc = fmaf((v).w, wd, acc);

#define MACC4(A, v, m)                \
    A.x = fmaf((v).x, m, A.x);        \
    A.y = fmaf((v).y, m, A.y);        \
    A.z = fmaf((v).z, m, A.z);        \
    A.w = fmaf((v).w, m, A.w);

#define RL(v, l) __int_as_float(__builtin_amdgcn_readlane(__float_as_int(v), (l)))

// acc += mean-quad(Areg @ lane ln) . (wa,wb,wc_,wd)
#define MEANFMA(acc, Areg, ln, wa, wb, wc_, wd)   \
    acc = fmaf(RL(Areg.x, ln), wa, acc);          \
    acc = fmaf(RL(Areg.y, ln), wb, acc);          \
    acc = fmaf(RL(Areg.z, ln), wc_, acc);         \
    acc = fmaf(RL(Areg.w, ln), wd, acc);

__global__ __launch_bounds__(512, 4) void k_flayer1(
    const float* __restrict__ x,      // [N][32]
    const int2* __restrict__ od,      // [2N] (off,deg)
    const int* __restrict__ elist,    // [E]
    const float* __restrict__ root1,  // [32][64]
    const float* __restrict__ W1,     // [2][32][64]
    const float* __restrict__ b1,     // [64]
    float* __restrict__ h1)           // [N][64]
{
    __shared__ float wR[IN_DIM * HID_DIM];
    __shared__ float w0[IN_DIM * HID_DIM];
    __shared__ float w1s[IN_DIM * HID_DIM];
    int tid = threadIdx.x;
    for (int i = tid; i < IN_DIM * HID_DIM; i += 512) {
        wR[i]  = root1[i];
        w0[i]  = W1[i];
        w1s[i] = W1[IN_DIM * HID_DIM + i];
    }

    int lane = tid & 63;
    int wv   = __builtin_amdgcn_readfirstlane(tid >> 6);
    int n0   = __builtin_amdgcn_readfirstlane(blockIdx.x * 32 + wv * 4);

    // 8 subgroups of 8 lanes: sub = r*4+i handles (node n0+i, rel r).
    int sub  = lane >> 3;
    int node = n0 + (sub & 3);
    int rel  = sub >> 2;
    int q    = lane & 7;          // feature quad 0..7 (features 4q..4q+3)
    int base = lane & 56;         // subgroup base lane

    int2 o = od[rel * N_NODES + node];
    int off = o.x, d = o.y;
    int erA = (q     < d) ? elist[off + q]     : 0;   // edges 0..7
    int erB = (8 + q < d) ? elist[off + 8 + q] : 0;   // edges 8..15

    int dm = d;
    dm = max(dm, __shfl_xor(dm, 8));
    dm = max(dm, __shfl_xor(dm, 16));
    dm = max(dm, __shfl_xor(dm, 32));           // wave max degree
    int kend = min(dm, 16);

    float4 A = make_float4(0.f, 0.f, 0.f, 0.f);
    for (int k = 0; k < kend; ++k) {
        int idx = (k < 8) ? __shfl(erA, base + k) : __shfl(erB, base + k - 8);
        float4 v = *(const float4*)(x + (size_t)idx * IN_DIM + q * 4);
        float m = (k < d) ? 1.0f : 0.0f;
        MACC4(A, v, m)
    }
    if (dm > 16) {                               // rare tail
        for (int k = 16; k < dm; ++k) {
            int idx = 0;
            if (k < d) idx = elist[off + k];
            float4 v = *(const float4*)(x + (size_t)idx * IN_DIM + q * 4);
            float m = (k < d) ? 1.0f : 0.0f;
            MACC4(A, v, m)
        }
    }
    float inv = 1.0f / fmaxf((float)d, 1.0f);
    A.x *= inv; A.y *= inv; A.z *= inv; A.w *= inv;
    // A = mean quad q of (node n0+(sub&3), rel sub>>2); lane (r*4+i)*8 + qq
    // holds quad qq -> readlane-addressable in the matmul.

    __syncthreads();   // weight staging complete

    // ---- matmul: self rows global, weights LDS, means via readlane ----
    int j = lane;
    const float* px = x + (size_t)n0 * IN_DIM;

    float accR0 = 0, accR1 = 0, accR2 = 0, accR3 = 0;
    float acc00 = 0, acc01 = 0, acc02 = 0, acc03 = 0;
    float acc10 = 0, acc11 = 0, acc12 = 0, acc13 = 0;

#pragma unroll 1
    for (int kk = 0; kk < IN_DIM / 4; ++kk) {
        int kbase = kk * 4;
        float4 xv0 = *(const float4*)(px + 0 * IN_DIM + kbase);
        float4 xv1 = *(const float4*)(px + 1 * IN_DIM + kbase);
        float4 xv2 = *(const float4*)(px + 2 * IN_DIM + kbase);
        float4 xv3 = *(const float4*)(px + 3 * IN_DIM + kbase);
        int wb_i = kbase * 64 + j;
        float wRa = wR[wb_i], wRb = wR[wb_i + 64], wRc = wR[wb_i + 128], wRd = wR[wb_i + 192];
        float w0a = w0[wb_i], w0b = w0[wb_i + 64], w0c = w0[wb_i + 128], w0d = w0[wb_i + 192];
        float w1a = w1s[wb_i], w1b = w1s[wb_i + 64], w1c = w1s[wb_i + 128], w1d = w1s[wb_i + 192];

        ACC4(accR0, xv0, wRa, wRb, wRc, wRd)
        ACC4(accR1, xv1, wRa, wRb, wRc, wRd)
        ACC4(accR2, xv2, wRa, wRb, wRc, wRd)
        ACC4(accR3, xv3, wRa, wRb, wRc, wRd)
        // rel0 means: subgroup i -> lanes i*8 + kk
        MEANFMA(acc00, A, 0 * 8 + kk, w0a, w0b, w0c, w0d)
        MEANFMA(acc01, A, 1 * 8 + kk, w0a, w0b, w0c, w0d)
        MEANFMA(acc02, A, 2 * 8 + kk, w0a, w0b, w0c, w0d)
        MEANFMA(acc03, A, 3 * 8 + kk, w0a, w0b, w0c, w0d)
        // rel1 means: subgroup 4+i -> lanes 32 + i*8 + kk
        MEANFMA(acc10, A, 32 + 0 * 8 + kk, w1a, w1b, w1c, w1d)
        MEANFMA(acc11, A, 32 + 1 * 8 + kk, w1a, w1b, w1c, w1d)
        MEANFMA(acc12, A, 32 + 2 * 8 + kk, w1a, w1b, w1c, w1d)
        MEANFMA(acc13, A, 32 + 3 * 8 + kk, w1a, w1b, w1c, w1d)
    }

    float bj = b1[j];
    h1[(size_t)(n0 + 0) * HID_DIM + j] = fmaxf(accR0 + bj + acc00 + acc10, 0.0f);
    h1[(size_t)(n0 + 1) * HID_DIM + j] = fmaxf(accR1 + bj + acc01 + acc11, 0.0f);
    h1[(size_t)(n0 + 2) * HID_DIM + j] = fmaxf(accR2 + bj + acc02 + acc12, 0.0f);
    h1[(size_t)(n0 + 3) * HID_DIM + j] = fmaxf(accR3 + bj + acc03 + acc13, 0.0f);
}

__global__ __launch_bounds__(512, 4) void k_flayer2(
    const float* __restrict__ h1,     // [N][64]
    const int2* __restrict__ od,
    const int* __restrict__ elist,
    const float* __restrict__ root2,  // [64][64] -- read from GLOBAL (L1-resident)
    const float* __restrict__ W2,     // [2][64][64]
    const float* __restrict__ b2,     // [64]
    const float* __restrict__ Wc,     // [64][2]
    const float* __restrict__ bc,     // [2]
    float* __restrict__ out)          // [N][2]
{
    __shared__ float w0[HID_DIM * HID_DIM];
    __shared__ float w1s[HID_DIM * HID_DIM];
    __shared__ float wc[HID_DIM * 2];
    int tid = threadIdx.x;
    for (int i = tid; i < HID_DIM * HID_DIM; i += 512) {
        w0[i]  = W2[i];
        w1s[i] = W2[HID_DIM * HID_DIM + i];
    }
    if (tid < HID_DIM * 2) wc[tid] = Wc[tid];

    int lane = tid & 63;
    int wv   = __builtin_amdgcn_readfirstlane(tid >> 6);
    int n0   = __builtin_amdgcn_readfirstlane(blockIdx.x * 32 + wv * 4);

    // 4 subgroups of 16 lanes: sub handles node n0+sub, both rels.
    int sub  = lane >> 4;
    int node = n0 + sub;
    int q    = lane & 15;         // feature quad 0..15
    int base = lane & 48;         // subgroup base lane

    int2 o0 = od[node];
    int2 o1 = od[N_NODES + node];
    int d0 = o0.y, d1 = o1.y;
    int er0 = (q < d0) ? elist[o0.x + q] : 0;   // edges 0..15 rel0
    int er1 = (q < d1) ? elist[o1.x + q] : 0;   // edges 0..15 rel1

    int dm = max(d0, d1);
    dm = max(dm, __shfl_xor(dm, 16));
    dm = max(dm, __shfl_xor(dm, 32));
    int kend = min(dm, 16);

    float4 A0 = make_float4(0.f, 0.f, 0.f, 0.f);
    float4 A1 = make_float4(0.f, 0.f, 0.f, 0.f);
    for (int k = 0; k < kend; ++k) {
        int i0 = __shfl(er0, base + k);
        int i1 = __shfl(er1, base + k);
        float4 v0 = *(const float4*)(h1 + (size_t)i0 * HID_DIM + q * 4);
        float4 v1 = *(const float4*)(h1 + (size_t)i1 * HID_DIM + q * 4);
        float m0 = (k < d0) ? 1.0f : 0.0f;
        float m1 = (k < d1) ? 1.0f : 0.0f;
        MACC4(A0, v0, m0)
        MACC4(A1, v1, m1)
    }
    if (dm > 16) {                               // rare tail
        for (int k = 16; k < dm; ++k) {
            int i0 = 0, i1 = 0;
            if (k < d0) i0 = elist[o0.x + k];
            if (k < d1) i1 = elist[o1.x + k];
            float4 v0 = *(const float4*)(h1 + (size_t)i0 * HID_DIM + q * 4);
            float4 v1 = *(const float4*)(h1 + (size_t)i1 * HID_DIM + q * 4);
            float m0 = (k < d0) ? 1.0f : 0.0f;
            float m1 = (k < d1) ? 1.0f : 0.0f;
            MACC4(A0, v0, m0)
            MACC4(A1, v1, m1)
        }
    }
    float i0v = 1.0f / fmaxf((float)d0, 1.0f);
    float i1v = 1.0f / fmaxf((float)d1, 1.0f);
    A0.x *= i0v; A0.y *= i0v; A0.z *= i0v; A0.w *= i0v;
    A1.x *= i1v; A1.y *= i1v; A1.z *= i1v; A1.w *= i1v;
    // A0/A1 = mean quad q of node n0+sub (rel0/rel1); quad qq at lane sub*16+qq.

    __syncthreads();   // weight staging complete

    // ---- matmul: self global, w0/w1s LDS, root2 global/L1, means readlane ----
    int j = lane;
    const float* px = h1 + (size_t)n0 * HID_DIM;

    float accR0 = 0, accR1 = 0, accR2 = 0, accR3 = 0;
    float acc00 = 0, acc01 = 0, acc02 = 0, acc03 = 0;
    float acc10 = 0, acc11 = 0, acc12 = 0, acc13 = 0;

#pragma unroll 1
    for (int kk = 0; kk < HID_DIM / 4; ++kk) {
        int kbase = kk * 4;
        float4 xv0 = *(const float4*)(px + 0 * HID_DIM + kbase);
        float4 xv1 = *(const float4*)(px + 1 * HID_DIM + kbase);
        float4 xv2 = *(const float4*)(px + 2 * HID_DIM + kbase);
        float4 xv3 = *(const float4*)(px + 3 * HID_DIM + kbase);
        int wb_i = kbase * 64 + j;
        float wRa = root2[wb_i], wRb = root2[wb_i + 64];
        float wRc = root2[wb_i + 128], wRd = root2[wb_i + 192];
        float w0a = w0[wb_i], w0b = w0[wb_i + 64], w0c = w0[wb_i + 128], w0d = w0[wb_i + 192];
        float w1a = w1s[wb_i], w1b = w1s[wb_i + 64], w1c = w1s[wb_i + 128], w1d = w1s[wb_i + 192];

        ACC4(accR0, xv0, wRa, wRb, wRc, wRd)
        ACC4(accR1, xv1, wRa, wRb, wRc, wRd)
        ACC4(accR2, xv2, wRa, wRb, wRc, wRd)
        ACC4(accR3, xv3, wRa, wRb, wRc, wRd)
        MEANFMA(acc00, A0, 0 * 16 + kk, w0a, w0b, w0c, w0d)
        MEANFMA(acc01, A0, 1 * 16 + kk, w0a, w0b, w0c, w0d)
        MEANFMA(acc02, A0, 2 * 16 + kk, w0a, w0b, w0c, w0d)
        MEANFMA(acc03, A0, 3 * 16 + kk, w0a, w0b, w0c, w0d)
        MEANFMA(acc10, A1, 0 * 16 + kk, w1a, w1b, w1c, w1d)
        MEANFMA(acc11, A1, 1 * 16 + kk, w1a, w1b, w1c, w1d)
        MEANFMA(acc12, A1, 2 * 16 + kk, w1a, w1b, w1c, w1d)
        MEANFMA(acc13, A1, 3 * 16 + kk, w1a, w1b, w1c, w1d)
    }

    float bj  = b2[j];
    float wcj0 = wc[2 * j], wcj1 = wc[2 * j + 1];
    float bc0 = bc[0], bc1 = bc[1];

#define L2_OUT(i, accR, acc0, acc1)                                           \
    {                                                                         \
        int n = n0 + i;                                                       \
        float h2 = fmaxf(accR + bj + acc0 + acc1, 0.0f);                      \
        float v0 = h2 * wcj0;                                                 \
        float v1 = h2 * wcj1;                                                 \
        for (int off = 32; off >= 1; off >>= 1) {                             \
            v0 += __shfl_xor(v0, off);                                        \
            v1 += __shfl_xor(v1, off);                                        \
        }                                                                     \
        if (j == 0) {                                                         \
            out[(size_t)n * 2 + 0] = v0 + bc0;                                \
            out[(size_t)n * 2 + 1] = v1 + bc1;                                \
        }                                                                     \
    }
    L2_OUT(0, accR0, acc00, acc10)
    L2_OUT(1, accR1, acc01, acc11)
    L2_OUT(2, accR2, acc02, acc12)
    L2_OUT(3, accR3, acc03, acc13)
#undef L2_OUT
}

// ============ launch ============

extern "C" void kernel_launch(void* const* d_in, const int* in_sizes, int n_in,
                              void* d_out, int out_size, void* d_ws, size_t ws_size,
                              hipStream_t stream) {
    const float* x     = (const float*)d_in[0];
    const int*   ei    = (const int*)d_in[1];
    const int*   ea    = (const int*)d_in[2];
    const float* W1    = (const float*)d_in[3];
    const float* root1 = (const float*)d_in[4];
    const float* b1    = (const float*)d_in[5];
    const float* W2    = (const float*)d_in[6];
    const float* root2 = (const float*)d_in[7];
    const float* b2    = (const float*)d_in[8];
    const float* Wc    = (const float*)d_in[9];
    const float* bc    = (const float*)d_in[10];
    float* out = (float*)d_out;

    // ws layout (bytes), peak ~33.6 MB:
    //   deg    @ 0        : 2N int  (800000)
    //   offs   @ 800000   : 2N int  (800000)
    //   od     @ 1600000  : 2N int2 (1600000)
    //   elist  @ 3200000  : E int   (4000000)
    //   h1     @ 7200000  : N*64 f32 (25600000)
    //   cursor @ 32800000 : 2N int  (800000)
    //   bsum   @ 33600000 : 1024 int
    char* ws = (char*)d_ws;
    int*   deg    = (int*)(ws);
    int*   offs   = (int*)(ws + 800000);
    int2*  od     = (int2*)(ws + 1600000);
    int*   elist  = (int*)(ws + 3200000);
    float* h1     = (float*)(ws + 7200000);
    int*   cursor = (int*)(ws + 32800000);
    int*   bsum   = (int*)(ws + 33600000);

    const int nblk_scan = (N2 + 255) / 256;                            // 782
    const int grid_cf   = ((N_EDGES + ECHUNK - 1) / ECHUNK) * NRANGE;  // 489*8

    hipMemsetAsync(deg, 0, (size_t)N2 * 4, stream);
    k_count<<<grid_cf, 256, 0, stream>>>(ei, ea, deg);
    k_scan_local<<<nblk_scan, 256, 0, stream>>>(deg, offs, bsum);
    k_scan_blocks<<<1, 64, 0, stream>>>(bsum, nblk_scan);
    k_scan_add<<<nblk_scan, 256, 0, stream>>>(offs, bsum, deg, cursor, od);
    k_fill<<<grid_cf, 256, 0, stream>>>(ei, ea, cursor, elist);

    k_flayer1<<<N_NODES / 32, 512, 0, stream>>>(x, od, elist, root1, W1, b1, h1);
    k_flayer2<<<N_NODES / 32, 512, 0, stream>>>(h1, od, elist, root2, W2, b2, Wc, bc, out);
}